// Round 4
// baseline (2721.058 us; speedup 1.0000x reference)
//
#include <hip/hip_runtime.h>
#include <hip/hip_bf16.h>

typedef __hip_bfloat16 bf16;
typedef __attribute__((ext_vector_type(8))) short short8;
typedef __attribute__((ext_vector_type(8))) __bf16 bf16x8;
typedef __attribute__((ext_vector_type(4))) float f32x4;

static __device__ __forceinline__ f32x4 mfma16(short8 a, short8 b, f32x4 c) {
  return __builtin_amdgcn_mfma_f32_16x16x32_bf16(
      __builtin_bit_cast(bf16x8, a), __builtin_bit_cast(bf16x8, b), c, 0, 0, 0);
}

// ---------------- elementwise f32 -> bf16 ----------------
__global__ __launch_bounds__(256) void k_f32_to_bf16(const float* __restrict__ in,
                                                     bf16* __restrict__ out, int n) {
  int i = blockIdx.x * 256 + threadIdx.x;
  if (i < n) out[i] = __float2bfloat16(in[i]);
}

// ---------------- tiled transpose+convert: out[n][k] = in[k][n] ----------------
__global__ __launch_bounds__(256) void k_transpose(const float* __restrict__ in,
                                                   bf16* __restrict__ out,
                                                   int K, int N, int ldo,
                                                   size_t inZ, size_t outZ) {
  in += (size_t)blockIdx.z * inZ;
  out += (size_t)blockIdx.z * outZ;
  __shared__ bf16 t[64][65];
  int k0 = blockIdx.x * 64, n0 = blockIdx.y * 64;
  for (int rep = 0; rep < 16; ++rep) {
    int lin = rep * 256 + threadIdx.x;
    int i = lin >> 6, j = lin & 63;
    if (k0 + i < K && n0 + j < N)
      t[i][j] = __float2bfloat16(in[(size_t)(k0 + i) * N + n0 + j]);
  }
  __syncthreads();
  for (int rep = 0; rep < 16; ++rep) {
    int lin = rep * 256 + threadIdx.x;
    int jj = lin >> 6, ii = lin & 63;
    if (n0 + jj < N && k0 + ii < K)
      out[(size_t)(n0 + jj) * ldo + k0 + ii] = t[ii][jj];
  }
}

// ---------------- workhorse NT GEMM ----------------
// C[m,n] = sum_k A[m,k]*BT[n,k], A: M x K (lda), BT: N x K (ldb). bf16 in, f32 acc.
// modes: 0 Cf=acc | 1 Cb=acc | 2 Cf=acc+resf | 3 Cb=silu(acc)*gates[m*10+e]
//        4 Cf=prevf+acc   (call sites choose Cf target; prevf may alias Cf)
__global__ __launch_bounds__(256) void k_gemm_nt(
    const bf16* __restrict__ A, const bf16* __restrict__ BT,
    int N, int K, int lda, int ldb, int ldc, int mode, int eidx,
    float* Cf, bf16* Cb,
    const float* __restrict__ resf, const float* prevf,
    const float* __restrict__ gates) {
  __shared__ bf16 As[128][40];
  __shared__ bf16 Bs[128][40];
  const int m0 = blockIdx.x * 128, n0 = blockIdx.y * 128;
  const int tid = threadIdx.x;
  const int lane = tid & 63, wave = tid >> 6;
  const int wr = (wave >> 1) * 64, wc = (wave & 1) * 64;
  const int lr = lane & 15, kg = (lane >> 4) * 8;
  const int sr = tid >> 1, sc = (tid & 1) * 16;

  f32x4 acc[4][4];
  for (int i = 0; i < 4; ++i)
    for (int j = 0; j < 4; ++j) acc[i][j] = f32x4{0.f, 0.f, 0.f, 0.f};

  int nr = n0 + sr; if (nr >= N) nr = N - 1;
  const bf16* Arow = A + (size_t)(m0 + sr) * lda + sc;
  const bf16* Brow = BT + (size_t)nr * ldb + sc;

  for (int k0 = 0; k0 < K; k0 += 32) {
    __syncthreads();
    short8 a0 = *(const short8*)(Arow + k0);
    short8 a1 = *(const short8*)(Arow + k0 + 8);
    short8 b0 = *(const short8*)(Brow + k0);
    short8 b1 = *(const short8*)(Brow + k0 + 8);
    *(short8*)&As[sr][sc] = a0;
    *(short8*)&As[sr][sc + 8] = a1;
    *(short8*)&Bs[sr][sc] = b0;
    *(short8*)&Bs[sr][sc + 8] = b1;
    __syncthreads();
    short8 af[4], bfr[4];
    for (int i = 0; i < 4; ++i) af[i] = *(const short8*)&As[wr + i * 16 + lr][kg];
    for (int j = 0; j < 4; ++j) bfr[j] = *(const short8*)&Bs[wc + j * 16 + lr][kg];
    for (int i = 0; i < 4; ++i)
      for (int j = 0; j < 4; ++j)
        acc[i][j] = mfma16(af[i], bfr[j], acc[i][j]);
  }

  for (int i = 0; i < 4; ++i) {
    int mb = m0 + wr + i * 16 + (lane >> 4) * 4;
    for (int j = 0; j < 4; ++j) {
      int n = n0 + wc + j * 16 + lr;
      if (n >= N) continue;
      for (int r = 0; r < 4; ++r) {
        size_t idx = (size_t)(mb + r) * ldc + n;
        float v = acc[i][j][r];
        if (mode == 0) Cf[idx] = v;
        else if (mode == 1) Cb[idx] = __float2bfloat16(v);
        else if (mode == 2) Cf[idx] = v + resf[idx];
        else if (mode == 3) {
          float g = gates[(size_t)(mb + r) * 10 + eidx];
          Cb[idx] = __float2bfloat16(g * (v / (1.f + __expf(-v))));
        } else Cf[idx] = prevf[idx] + v;
      }
    }
  }
}

// ---------------- post GEMM0: rmsnorms + split, write kv output (f32) ----------------
__global__ __launch_bounds__(256) void k_postproj1(
    const float* __restrict__ tmp, const float* __restrict__ qnw,
    const float* __restrict__ kvnw, bf16* __restrict__ cq,
    bf16* __restrict__ kvn, float* __restrict__ krope, float* __restrict__ kvout) {
  int t = blockIdx.x * 4 + (threadIdx.x >> 6);
  int lane = threadIdx.x & 63;
  const float* row = tmp + (size_t)t * 352;
  float s1 = 0.f, s2 = 0.f;
  for (int d = lane; d < 192; d += 64) { float v = row[d]; s1 += v * v; }
  for (int d = lane; d < 128; d += 64) { float v = row[192 + d]; s2 += v * v; }
  for (int o = 32; o > 0; o >>= 1) { s1 += __shfl_xor(s1, o); s2 += __shfl_xor(s2, o); }
  float r1 = rsqrtf(s1 / 192.f + 1e-6f);
  float r2 = rsqrtf(s2 / 128.f + 1e-6f);
  for (int d = lane; d < 192; d += 64)
    cq[(size_t)t * 192 + d] = __float2bfloat16(row[d] * r1 * qnw[d]);
  for (int d = lane; d < 128; d += 64)
    kvn[(size_t)t * 128 + d] = __float2bfloat16(row[192 + d] * r2 * kvnw[d]);
  for (int d = lane; d < 160; d += 64)
    kvout[(size_t)t * 160 + d] = row[192 + d];
  if (lane < 32) krope[(size_t)t * 32 + lane] = row[320 + lane];
}

// ---------------- q: rope + pack to [bh][s][96] ----------------
__global__ __launch_bounds__(256) void k_rope_q(const float* __restrict__ qraw,
                                                bf16* __restrict__ qf) {
  int idx = blockIdx.x * 256 + threadIdx.x;  // 8192*384
  int t = idx / 384, hd = idx - t * 384;
  int h = hd / 96, d = hd - h * 96;
  int s = t & 2047;
  const float* q = qraw + (size_t)t * 384 + h * 96;
  float v;
  if (d < 64) v = q[d];
  else {
    int j = d - 64, jm = j & 15;
    float invf = expf(-(float)jm * 0.575646273f);  // 10000^(-jm/16)
    float ang = (float)s * invf;
    float c = cosf(ang), sn = sinf(ang);
    float x1 = q[64 + jm], x2 = q[80 + jm];
    v = (j < 16) ? (x1 * c - x2 * sn) : (x2 * c + x1 * sn);
  }
  size_t bh = (size_t)(t >> 11) * 4 + h;
  qf[bh * (2048 * 96) + (size_t)s * 96 + d] = __float2bfloat16(v);
}

// ---------------- k: nope copy + shared roped k_rope, pack to [bh][s][96] ----------------
__global__ __launch_bounds__(256) void k_make_kf(const bf16* __restrict__ kvbig,
                                                 const float* __restrict__ krope,
                                                 bf16* __restrict__ kf) {
  int idx = blockIdx.x * 256 + threadIdx.x;
  int t = idx / 384, hd = idx - t * 384;
  int h = hd / 96, d = hd - h * 96;
  int s = t & 2047;
  bf16 outv;
  if (d < 64) outv = kvbig[(size_t)t * 768 + h * 192 + d];
  else {
    int j = d - 64, jm = j & 15;
    float invf = expf(-(float)jm * 0.575646273f);
    float ang = (float)s * invf;
    float c = cosf(ang), sn = sinf(ang);
    float x1 = krope[(size_t)t * 32 + jm], x2 = krope[(size_t)t * 32 + 16 + jm];
    float v = (j < 16) ? (x1 * c - x2 * sn) : (x2 * c + x1 * sn);
    outv = __float2bfloat16(v);
  }
  size_t bh = (size_t)(t >> 11) * 4 + h;
  kf[bh * (2048 * 96) + (size_t)s * 96 + d] = outv;
}

// ---------------- v: extract + transpose to [bh][d=128][s=2048] ----------------
__global__ __launch_bounds__(256) void k_make_vT(const bf16* __restrict__ kvbig,
                                                 bf16* __restrict__ vT) {
  __shared__ bf16 t[64][136];
  int bh = blockIdx.y;
  int b = bh >> 2, h = bh & 3;
  int s0 = blockIdx.x * 64;
  for (int rep = 0; rep < 4; ++rep) {
    int lin = rep * 256 + threadIdx.x;
    int i = lin >> 4, jc = (lin & 15) * 8;
    short8 v = *(const short8*)(kvbig + (size_t)(b * 2048 + s0 + i) * 768 + h * 192 + 64 + jc);
    *(short8*)&t[i][jc] = v;
  }
  __syncthreads();
  for (int rep = 0; rep < 32; ++rep) {
    int lin = rep * 256 + threadIdx.x;
    int d = lin >> 6, i = lin & 63;
    vT[((size_t)bh * 128 + d) * 2048 + s0 + i] = t[i][d];
  }
}

// ---------------- flash attention: 1 wave / 32 queries ----------------
__global__ __launch_bounds__(64) void k_flash(const bf16* __restrict__ qf,
                                              const bf16* __restrict__ kf,
                                              const bf16* __restrict__ vT,
                                              bf16* __restrict__ attn) {
  const int bh = blockIdx.y;
  const int q0 = blockIdx.x * 32;
  const int lane = threadIdx.x;
  const int lr = lane & 15, kg = (lane >> 4) * 8;
  const bf16* Q  = qf + (size_t)bh * (2048 * 96);
  const bf16* Kp = kf + (size_t)bh * (2048 * 96);
  const bf16* Vt = vT + (size_t)bh * (128 * 2048);

  short8 qfr[2][3];
  for (int i = 0; i < 2; ++i)
    for (int ks = 0; ks < 3; ++ks)
      qfr[i][ks] = *(const short8*)(Q + (size_t)(q0 + i * 16 + lr) * 96 + ks * 32 + kg);

  f32x4 o[2][8];
  for (int i = 0; i < 2; ++i)
    for (int j = 0; j < 8; ++j) o[i][j] = f32x4{0.f, 0.f, 0.f, 0.f};
  float mrow[2][4], lsum[2][4];
  for (int i = 0; i < 2; ++i)
    for (int r = 0; r < 4; ++r) { mrow[i][r] = -1e30f; lsum[i][r] = 0.f; }

  __shared__ bf16 plds[32][40];
  const float scale = 0.1020620726f;  // 1/sqrt(96)
  const int nkt = q0 / 32 + 1;

  for (int kt = 0; kt < nkt; ++kt) {
    int kv0 = kt * 32;
    f32x4 s[2][2];
    for (int i = 0; i < 2; ++i)
      for (int j = 0; j < 2; ++j) s[i][j] = f32x4{0.f, 0.f, 0.f, 0.f};
    for (int j = 0; j < 2; ++j)
      for (int ks = 0; ks < 3; ++ks) {
        short8 kfr = *(const short8*)(Kp + (size_t)(kv0 + j * 16 + lr) * 96 + ks * 32 + kg);
        s[0][j] = mfma16(qfr[0][ks], kfr, s[0][j]);
        s[1][j] = mfma16(qfr[1][ks], kfr, s[1][j]);
      }
    bool diag = (kt == nkt - 1);
    for (int i = 0; i < 2; ++i)
      for (int j = 0; j < 2; ++j)
        for (int r = 0; r < 4; ++r) {
          float v = s[i][j][r] * scale;
          if (diag) {
            int qq = q0 + i * 16 + (lane >> 4) * 4 + r;
            int kk = kv0 + j * 16 + lr;
            if (kk > qq) v = -1e30f;
          }
          s[i][j][r] = v;
        }
    for (int i = 0; i < 2; ++i)
      for (int r = 0; r < 4; ++r) {
        float v = fmaxf(s[i][0][r], s[i][1][r]);
        v = fmaxf(v, __shfl_xor(v, 1));
        v = fmaxf(v, __shfl_xor(v, 2));
        v = fmaxf(v, __shfl_xor(v, 4));
        v = fmaxf(v, __shfl_xor(v, 8));
        float mnew = fmaxf(mrow[i][r], v);
        float alpha = __expf(mrow[i][r] - mnew);
        mrow[i][r] = mnew;
        float p0 = __expf(s[i][0][r] - mnew);
        float p1 = __expf(s[i][1][r] - mnew);
        s[i][0][r] = p0; s[i][1][r] = p1;
        float rs = p0 + p1;
        rs += __shfl_xor(rs, 1); rs += __shfl_xor(rs, 2);
        rs += __shfl_xor(rs, 4); rs += __shfl_xor(rs, 8);
        lsum[i][r] = lsum[i][r] * alpha + rs;
        for (int j = 0; j < 8; ++j) o[i][j][r] *= alpha;
      }
    __syncthreads();
    for (int i = 0; i < 2; ++i)
      for (int j = 0; j < 2; ++j)
        for (int r = 0; r < 4; ++r)
          plds[i * 16 + (lane >> 4) * 4 + r][j * 16 + lr] = __float2bfloat16(s[i][j][r]);
    __syncthreads();
    short8 pf0 = *(const short8*)&plds[lr][kg];
    short8 pf1 = *(const short8*)&plds[16 + lr][kg];
    for (int j = 0; j < 8; ++j) {
      short8 vf = *(const short8*)(Vt + (size_t)(j * 16 + lr) * 2048 + kv0 + kg);
      o[0][j] = mfma16(pf0, vf, o[0][j]);
      o[1][j] = mfma16(pf1, vf, o[1][j]);
    }
  }
  int b = bh >> 2, h = bh & 3;
  for (int i = 0; i < 2; ++i)
    for (int r = 0; r < 4; ++r) {
      int qq = q0 + i * 16 + (lane >> 4) * 4 + r;
      float inv = 1.f / lsum[i][r];
      size_t base = ((size_t)(b * 2048 + qq)) * 512 + h * 128;
      for (int j = 0; j < 8; ++j)
        attn[base + j * 16 + lr] = __float2bfloat16(o[i][j][r] * inv);
    }
}

// ---------------- rmsnorm #2 ----------------
__global__ __launch_bounds__(256) void k_norm2(const float* __restrict__ x1,
                                               const float* __restrict__ w,
                                               float* __restrict__ x2f,
                                               bf16* __restrict__ x2b) {
  int t = blockIdx.x * 4 + (threadIdx.x >> 6);
  int lane = threadIdx.x & 63;
  const float* row = x1 + (size_t)t * 512;
  float ss = 0.f;
  for (int d = lane; d < 512; d += 64) { float v = row[d]; ss += v * v; }
  for (int o = 32; o > 0; o >>= 1) ss += __shfl_xor(ss, o);
  float rr = rsqrtf(ss / 512.f + 1e-6f);
  for (int d = lane; d < 512; d += 64) {
    float v = row[d] * rr * w[d];
    x2f[(size_t)t * 512 + d] = v;
    x2b[(size_t)t * 512 + d] = __float2bfloat16(v);
  }
}

// ---------------- MoE gating: softmax + top2 -> gates[t][10] ----------------
__global__ __launch_bounds__(256) void k_gating(const float* __restrict__ x2f,
                                                const float* __restrict__ Wg,
                                                float* __restrict__ gates) {
  __shared__ float lg[4][8];
  int wv = threadIdx.x >> 6;
  int t = blockIdx.x * 4 + wv;
  int lane = threadIdx.x & 63;
  int e = lane >> 3, p = lane & 7;
  const float* row = x2f + (size_t)t * 512;
  float sacc = 0.f;
  for (int i = 0; i < 64; ++i) {
    int d = p * 64 + i;
    sacc += row[d] * Wg[d * 8 + e];
  }
  sacc += __shfl_xor(sacc, 1);
  sacc += __shfl_xor(sacc, 2);
  sacc += __shfl_xor(sacc, 4);
  if (p == 0) lg[wv][e] = sacc;
  __syncthreads();
  float pr[8];
  float mx = -1e30f;
  for (int i = 0; i < 8; ++i) { pr[i] = lg[wv][i]; mx = fmaxf(mx, pr[i]); }
  for (int i = 0; i < 8; ++i) pr[i] = __expf(pr[i] - mx);
  int i1 = 0; float v1 = pr[0];
  for (int i = 1; i < 8; ++i) if (pr[i] > v1) { v1 = pr[i]; i1 = i; }
  int i2 = -1; float v2 = -1.f;
  for (int i = 0; i < 8; ++i) if (i != i1 && pr[i] > v2) { v2 = pr[i]; i2 = i; }
  float wsum = v1 + v2;
  if (lane < 10) {
    float g = 1.f;  // shared experts (slots 8,9)
    if (lane < 8) g = (lane == i1) ? v1 / wsum : ((lane == i2) ? v2 / wsum : 0.f);
    gates[(size_t)t * 10 + lane] = g;
  }
}

// ---------------- host ----------------
extern "C" void kernel_launch(void* const* d_in, const int* in_sizes, int n_in,
                              void* d_out, int out_size, void* d_ws, size_t ws_size,
                              hipStream_t stream) {
  const float* x    = (const float*)d_in[0];
  const float* n2w  = (const float*)d_in[1];
  const float* Wdq  = (const float*)d_in[2];
  const float* qnw  = (const float*)d_in[3];
  const float* Wuq  = (const float*)d_in[4];
  const float* Wdkv = (const float*)d_in[5];
  const float* kvnw = (const float*)d_in[6];
  const float* Wukv = (const float*)d_in[7];
  const float* Wo   = (const float*)d_in[8];
  const float* Wg   = (const float*)d_in[9];
  const float* We1  = (const float*)d_in[10];
  const float* We2  = (const float*)d_in[11];
  const float* Ws1  = (const float*)d_in[12];
  const float* Ws2  = (const float*)d_in[13];

  // OUTPUTS ARE FLOAT32 (out_npz 20.4MB == f32 size; bf16 would be ~half).
  float* out_x  = (float*)d_out;
  float* out_kv = out_x + (size_t)4 * 2048 * 512;

  char* base = (char*)d_ws;
  size_t off = 0;
  auto alloc = [&](size_t bytes) -> void* {
    void* p = base + off;
    off += (bytes + 255) & ~(size_t)255;
    return p;
  };
  const size_t T = 8192;
  bf16*  xb    = (bf16*)alloc(T * 512 * 2);
  bf16*  WcatT = (bf16*)alloc(352 * 512 * 2);
  bf16*  WuqT  = (bf16*)alloc(384 * 192 * 2);
  bf16*  WukvT = (bf16*)alloc(768 * 128 * 2);
  bf16*  WoT   = (bf16*)alloc(512 * 512 * 2);
  bf16*  W1T   = (bf16*)alloc((size_t)10 * 1024 * 512 * 2);
  bf16*  W2T   = (bf16*)alloc((size_t)10 * 512 * 1024 * 2);
  float* tmp0  = (float*)alloc(T * 352 * 4);
  bf16*  cq    = (bf16*)alloc(T * 192 * 2);
  bf16*  kvn   = (bf16*)alloc(T * 128 * 2);
  float* krope = (float*)alloc(T * 32 * 4);
  float* qraw  = (float*)alloc(T * 384 * 4);
  bf16*  kvbig = (bf16*)alloc(T * 768 * 2);
  bf16*  qf    = (bf16*)alloc(T * 384 * 2);
  bf16*  kf    = (bf16*)alloc(T * 384 * 2);
  bf16*  vT    = (bf16*)alloc(T * 512 * 2);
  bf16*  attnb = (bf16*)alloc(T * 512 * 2);
  float* x1f   = (float*)alloc(T * 512 * 4);
  float* x2f   = (float*)alloc(T * 512 * 4);
  bf16*  x2b   = (bf16*)alloc(T * 512 * 2);
  float* gates = (float*)alloc(T * 10 * 4);
  bf16*  Hbuf  = (bf16*)alloc(T * 1024 * 2);
  float* moeacc = x1f;  // alias: x1f is dead after k_norm2

  if (off > ws_size) return;

  // x -> bf16
  k_f32_to_bf16<<<(int)((T * 512 + 255) / 256), 256, 0, stream>>>(x, xb, (int)(T * 512));

  // weight transposes (f32 -> bf16, N x K)
  k_transpose<<<dim3(8, 3, 1), 256, 0, stream>>>(Wdq,  WcatT,             512, 192, 512, 0, 0);
  k_transpose<<<dim3(8, 3, 1), 256, 0, stream>>>(Wdkv, WcatT + 192 * 512, 512, 160, 512, 0, 0);
  k_transpose<<<dim3(3, 6, 1), 256, 0, stream>>>(Wuq,  WuqT,  192, 384, 192, 0, 0);
  k_transpose<<<dim3(2, 12, 1), 256, 0, stream>>>(Wukv, WukvT, 128, 768, 128, 0, 0);
  k_transpose<<<dim3(8, 8, 1), 256, 0, stream>>>(Wo,   WoT,   512, 512, 512, 0, 0);
  k_transpose<<<dim3(8, 16, 8), 256, 0, stream>>>(We1, W1T, 512, 1024, 512,
                                                  (size_t)512 * 1024, (size_t)1024 * 512);
  k_transpose<<<dim3(8, 16, 2), 256, 0, stream>>>(Ws1, W1T + (size_t)8 * 1024 * 512, 512, 1024, 512,
                                                  (size_t)512 * 1024, (size_t)1024 * 512);
  k_transpose<<<dim3(16, 8, 8), 256, 0, stream>>>(We2, W2T, 1024, 512, 1024,
                                                  (size_t)1024 * 512, (size_t)512 * 1024);
  k_transpose<<<dim3(16, 8, 2), 256, 0, stream>>>(Ws2, W2T + (size_t)8 * 512 * 1024, 1024, 512, 1024,
                                                  (size_t)1024 * 512, (size_t)512 * 1024);

  // x @ [W_dq | W_dkv] -> tmp0 (f32), then norms/splits (+ f32 kv output)
  k_gemm_nt<<<dim3(64, 3), 256, 0, stream>>>(xb, WcatT, 352, 512, 512, 512, 352, 0, 0,
                                             tmp0, nullptr, nullptr, nullptr, nullptr);
  k_postproj1<<<2048, 256, 0, stream>>>(tmp0, qnw, kvnw, cq, kvn, krope, out_kv);

  // q path
  k_gemm_nt<<<dim3(64, 3), 256, 0, stream>>>(cq, WuqT, 384, 192, 192, 192, 384, 0, 0,
                                             qraw, nullptr, nullptr, nullptr, nullptr);
  k_rope_q<<<12288, 256, 0, stream>>>(qraw, qf);

  // kv path
  k_gemm_nt<<<dim3(64, 6), 256, 0, stream>>>(kvn, WukvT, 768, 128, 128, 128, 768, 1, 0,
                                             nullptr, kvbig, nullptr, nullptr, nullptr);
  k_make_kf<<<12288, 256, 0, stream>>>(kvbig, krope, kf);
  k_make_vT<<<dim3(32, 16), 256, 0, stream>>>(kvbig, vT);

  // attention
  k_flash<<<dim3(64, 16), 64, 0, stream>>>(qf, kf, vT, attnb);

  // W_o + residual, norm2, gating
  k_gemm_nt<<<dim3(64, 4), 256, 0, stream>>>(attnb, WoT, 512, 512, 512, 512, 512, 2, 0,
                                             x1f, nullptr, x, nullptr, nullptr);
  k_norm2<<<2048, 256, 0, stream>>>(x1f, n2w, x2f, x2b);
  k_gating<<<2048, 256, 0, stream>>>(x2f, Wg, gates);

  // MoE: dense over 8 routed + 2 shared experts
  for (int e = 0; e < 10; ++e) {
    k_gemm_nt<<<dim3(64, 8), 256, 0, stream>>>(x2b, W1T + (size_t)e * 1024 * 512,
                                               1024, 512, 512, 512, 1024, 3, e,
                                               nullptr, Hbuf, nullptr, nullptr, gates);
    // mode 4: Cf = prevf + acc. e<9 accumulates into moeacc; e==9 writes f32 out_x.
    float* dst = (e == 9) ? out_x : moeacc;
    const float* prev = (e == 0) ? x2f : moeacc;
    k_gemm_nt<<<dim3(64, 4), 256, 0, stream>>>(Hbuf, W2T + (size_t)e * 512 * 1024,
                                               512, 1024, 1024, 1024, 512, 4, 0,
                                               dst, nullptr, nullptr, prev, nullptr);
  }
}

// Round 5
// 2621.614 us; speedup vs baseline: 1.0379x; 1.0379x over previous
//
#include <hip/hip_runtime.h>
#include <hip/hip_bf16.h>

typedef __hip_bfloat16 bf16;
typedef __attribute__((ext_vector_type(8))) short short8;
typedef __attribute__((ext_vector_type(8))) __bf16 bf16x8;
typedef __attribute__((ext_vector_type(4))) float f32x4;

static __device__ __forceinline__ f32x4 mfma16(short8 a, short8 b, f32x4 c) {
  return __builtin_amdgcn_mfma_f32_16x16x32_bf16(
      __builtin_bit_cast(bf16x8, a), __builtin_bit_cast(bf16x8, b), c, 0, 0, 0);
}

// async global->LDS, 16B per lane. LDS dest must be wave-uniform base; HW adds lane*16.
static __device__ __forceinline__ void gload16(const bf16* g, void* l) {
  __builtin_amdgcn_global_load_lds(
      (const __attribute__((address_space(1))) void*)g,
      (__attribute__((address_space(3))) void*)l, 16, 0, 0);
}

// ---------------- elementwise f32 -> bf16 ----------------
__global__ __launch_bounds__(256) void k_f32_to_bf16(const float* __restrict__ in,
                                                     bf16* __restrict__ out, int n) {
  int i = blockIdx.x * 256 + threadIdx.x;
  if (i < n) out[i] = __float2bfloat16(in[i]);
}

// ---------------- tiled transpose+convert: out[n][k] = in[k][n] ----------------
__global__ __launch_bounds__(256) void k_transpose(const float* __restrict__ in,
                                                   bf16* __restrict__ out,
                                                   int K, int N, int ldo,
                                                   size_t inZ, size_t outZ) {
  in += (size_t)blockIdx.z * inZ;
  out += (size_t)blockIdx.z * outZ;
  __shared__ bf16 t[64][65];
  int k0 = blockIdx.x * 64, n0 = blockIdx.y * 64;
  for (int rep = 0; rep < 16; ++rep) {
    int lin = rep * 256 + threadIdx.x;
    int i = lin >> 6, j = lin & 63;
    if (k0 + i < K && n0 + j < N)
      t[i][j] = __float2bfloat16(in[(size_t)(k0 + i) * N + n0 + j]);
  }
  __syncthreads();
  for (int rep = 0; rep < 16; ++rep) {
    int lin = rep * 256 + threadIdx.x;
    int jj = lin >> 6, ii = lin & 63;
    if (n0 + jj < N && k0 + ii < K)
      out[(size_t)(n0 + jj) * ldo + k0 + ii] = t[ii][jj];
  }
}

// ---------------- workhorse NT GEMM (m97 structure: global_load_lds, linear LDS) ----
// C[m,n] = sum_k A[m,k]*BT[n,k], A: M x K (lda), BT: N x K (ldb). bf16 in, f32 acc.
// modes: 0 Cf=acc | 1 Cb=acc | 2 Cf=acc+resf | 3 Cb=silu(acc)*gates[m*10+e]
//        4 Cf=prevf+acc
// NOTE: B staging reads rows [n0, n0+128) unconditionally; for N=352 this overruns
// into the adjacent ws buffer (harmless garbage, outputs discarded by n>=N guard).
__global__ __launch_bounds__(256) void k_gemm_nt(
    const bf16* __restrict__ A, const bf16* __restrict__ BT,
    int N, int K, int lda, int ldb, int ldc, int mode, int eidx,
    float* Cf, bf16* Cb,
    const float* __restrict__ resf, const float* prevf,
    const float* __restrict__ gates) {
  __shared__ __align__(16) bf16 As[128 * 32];
  __shared__ __align__(16) bf16 Bs[128 * 32];
  const int m0 = blockIdx.x * 128, n0 = blockIdx.y * 128;
  const int tid = threadIdx.x;
  const int lane = tid & 63, wave = tid >> 6;
  const int wr = (wave >> 1) * 64, wc = (wave & 1) * 64;
  const int lr = lane & 15, kg = (lane >> 4) * 8;

  // staging: issue i covers LDS bytes [(i*4+wave)*1024 + lane*16); row=(i*64+wave*16+lane/4)
  const int srow = wave * 16 + (lane >> 2);
  const int scol = (lane & 3) * 8;
  const bf16* Ab = A + (size_t)(m0 + srow) * lda + scol;
  const bf16* Bb = BT + (size_t)(n0 + srow) * ldb + scol;
  char* AsL = (char*)As + wave * 1024;
  char* BsL = (char*)Bs + wave * 1024;

  f32x4 acc[4][4];
  for (int i = 0; i < 4; ++i)
    for (int j = 0; j < 4; ++j) acc[i][j] = f32x4{0.f, 0.f, 0.f, 0.f};

  for (int k0 = 0; k0 < K; k0 += 32) {
    __syncthreads();
    gload16(Ab + k0, AsL);
    gload16(Ab + (size_t)64 * lda + k0, AsL + 4096);
    gload16(Bb + k0, BsL);
    gload16(Bb + (size_t)64 * ldb + k0, BsL + 4096);
    __syncthreads();  // compiler drains vmcnt before barrier -> tile visible
    short8 af[4], bfr[4];
    for (int i = 0; i < 4; ++i) af[i] = *(const short8*)&As[(wr + i * 16 + lr) * 32 + kg];
    for (int j = 0; j < 4; ++j) bfr[j] = *(const short8*)&Bs[(wc + j * 16 + lr) * 32 + kg];
    for (int i = 0; i < 4; ++i)
      for (int j = 0; j < 4; ++j)
        acc[i][j] = mfma16(af[i], bfr[j], acc[i][j]);
  }

  for (int i = 0; i < 4; ++i) {
    int mb = m0 + wr + i * 16 + (lane >> 4) * 4;
    for (int j = 0; j < 4; ++j) {
      int n = n0 + wc + j * 16 + lr;
      if (n >= N) continue;
      for (int r = 0; r < 4; ++r) {
        size_t idx = (size_t)(mb + r) * ldc + n;
        float v = acc[i][j][r];
        if (mode == 0) Cf[idx] = v;
        else if (mode == 1) Cb[idx] = __float2bfloat16(v);
        else if (mode == 2) Cf[idx] = v + resf[idx];
        else if (mode == 3) {
          float g = gates[(size_t)(mb + r) * 10 + eidx];
          Cb[idx] = __float2bfloat16(g * (v / (1.f + __expf(-v))));
        } else Cf[idx] = prevf[idx] + v;
      }
    }
  }
}

// ---------------- post GEMM0: rmsnorms + split, write kv output (f32) ----------------
__global__ __launch_bounds__(256) void k_postproj1(
    const float* __restrict__ tmp, const float* __restrict__ qnw,
    const float* __restrict__ kvnw, bf16* __restrict__ cq,
    bf16* __restrict__ kvn, float* __restrict__ krope, float* __restrict__ kvout) {
  int t = blockIdx.x * 4 + (threadIdx.x >> 6);
  int lane = threadIdx.x & 63;
  const float* row = tmp + (size_t)t * 352;
  float s1 = 0.f, s2 = 0.f;
  for (int d = lane; d < 192; d += 64) { float v = row[d]; s1 += v * v; }
  for (int d = lane; d < 128; d += 64) { float v = row[192 + d]; s2 += v * v; }
  for (int o = 32; o > 0; o >>= 1) { s1 += __shfl_xor(s1, o); s2 += __shfl_xor(s2, o); }
  float r1 = rsqrtf(s1 / 192.f + 1e-6f);
  float r2 = rsqrtf(s2 / 128.f + 1e-6f);
  for (int d = lane; d < 192; d += 64)
    cq[(size_t)t * 192 + d] = __float2bfloat16(row[d] * r1 * qnw[d]);
  for (int d = lane; d < 128; d += 64)
    kvn[(size_t)t * 128 + d] = __float2bfloat16(row[192 + d] * r2 * kvnw[d]);
  for (int d = lane; d < 160; d += 64)
    kvout[(size_t)t * 160 + d] = row[192 + d];
  if (lane < 32) krope[(size_t)t * 32 + lane] = row[320 + lane];
}

// ---------------- rope cos/sin table: tab[s][0..15]=cos, [16..31]=sin ----------------
__global__ __launch_bounds__(256) void k_rope_table(float* __restrict__ tab) {
  int idx = blockIdx.x * 256 + threadIdx.x;  // 2048*16
  int s = idx >> 4, jm = idx & 15;
  float invf = expf(-(float)jm * 0.575646273f);  // 10000^(-jm/16)
  float ang = (float)s * invf;
  tab[s * 32 + jm] = cosf(ang);
  tab[s * 32 + 16 + jm] = sinf(ang);
}

// ---------------- q: rope + pack to [bh][s][96] ----------------
__global__ __launch_bounds__(256) void k_rope_q(const float* __restrict__ qraw,
                                                const float* __restrict__ tab,
                                                bf16* __restrict__ qf) {
  int idx = blockIdx.x * 256 + threadIdx.x;  // 8192*384
  int t = idx / 384, hd = idx - t * 384;
  int h = hd / 96, d = hd - h * 96;
  int s = t & 2047;
  const float* q = qraw + (size_t)t * 384 + h * 96;
  float v;
  if (d < 64) v = q[d];
  else {
    int j = d - 64, jm = j & 15;
    float c = tab[s * 32 + jm], sn = tab[s * 32 + 16 + jm];
    float x1 = q[64 + jm], x2 = q[80 + jm];
    v = (j < 16) ? (x1 * c - x2 * sn) : (x2 * c + x1 * sn);
  }
  size_t bh = (size_t)(t >> 11) * 4 + h;
  qf[bh * (2048 * 96) + (size_t)s * 96 + d] = __float2bfloat16(v);
}

// ---------------- k: nope copy + shared roped k_rope, pack to [bh][s][96] ----------------
__global__ __launch_bounds__(256) void k_make_kf(const bf16* __restrict__ kvbig,
                                                 const float* __restrict__ krope,
                                                 const float* __restrict__ tab,
                                                 bf16* __restrict__ kf) {
  int idx = blockIdx.x * 256 + threadIdx.x;
  int t = idx / 384, hd = idx - t * 384;
  int h = hd / 96, d = hd - h * 96;
  int s = t & 2047;
  bf16 outv;
  if (d < 64) outv = kvbig[(size_t)t * 768 + h * 192 + d];
  else {
    int j = d - 64, jm = j & 15;
    float c = tab[s * 32 + jm], sn = tab[s * 32 + 16 + jm];
    float x1 = krope[(size_t)t * 32 + jm], x2 = krope[(size_t)t * 32 + 16 + jm];
    float v = (j < 16) ? (x1 * c - x2 * sn) : (x2 * c + x1 * sn);
    outv = __float2bfloat16(v);
  }
  size_t bh = (size_t)(t >> 11) * 4 + h;
  kf[bh * (2048 * 96) + (size_t)s * 96 + d] = outv;
}

// ---------------- v: extract + transpose to [bh][d=128][s=2048] ----------------
__global__ __launch_bounds__(256) void k_make_vT(const bf16* __restrict__ kvbig,
                                                 bf16* __restrict__ vT) {
  __shared__ bf16 t[64][136];
  int bh = blockIdx.y;
  int b = bh >> 2, h = bh & 3;
  int s0 = blockIdx.x * 64;
  for (int rep = 0; rep < 4; ++rep) {
    int lin = rep * 256 + threadIdx.x;
    int i = lin >> 4, jc = (lin & 15) * 8;
    short8 v = *(const short8*)(kvbig + (size_t)(b * 2048 + s0 + i) * 768 + h * 192 + 64 + jc);
    *(short8*)&t[i][jc] = v;
  }
  __syncthreads();
  for (int rep = 0; rep < 32; ++rep) {
    int lin = rep * 256 + threadIdx.x;
    int d = lin >> 6, i = lin & 63;
    vT[((size_t)bh * 128 + d) * 2048 + s0 + i] = t[i][d];
  }
}

// ---------------- flash attention: 1 wave / 32 queries, K/V register prefetch ------
__global__ __launch_bounds__(64, 1) void k_flash(const bf16* __restrict__ qf,
                                                 const bf16* __restrict__ kf,
                                                 const bf16* __restrict__ vT,
                                                 bf16* __restrict__ attn) {
  const int bh = blockIdx.y;
  const int q0 = blockIdx.x * 32;
  const int lane = threadIdx.x;
  const int lr = lane & 15, kg = (lane >> 4) * 8;
  const bf16* Q  = qf + (size_t)bh * (2048 * 96);
  const bf16* Kp = kf + (size_t)bh * (2048 * 96);
  const bf16* Vt = vT + (size_t)bh * (128 * 2048);

  short8 qfr[2][3];
  for (int i = 0; i < 2; ++i)
    for (int ks = 0; ks < 3; ++ks)
      qfr[i][ks] = *(const short8*)(Q + (size_t)(q0 + i * 16 + lr) * 96 + ks * 32 + kg);

  f32x4 o[2][8];
  for (int i = 0; i < 2; ++i)
    for (int j = 0; j < 8; ++j) o[i][j] = f32x4{0.f, 0.f, 0.f, 0.f};
  float mrow[2][4], lsum[2][4];
  for (int i = 0; i < 2; ++i)
    for (int r = 0; r < 4; ++r) { mrow[i][r] = -1e30f; lsum[i][r] = 0.f; }

  __shared__ bf16 plds[32][40];
  const float scale = 0.1020620726f;  // 1/sqrt(96)
  const int nkt = q0 / 32 + 1;

  // preload tile 0 into registers
  short8 kc[2][3], vc[8];
  for (int j = 0; j < 2; ++j)
    for (int ks = 0; ks < 3; ++ks)
      kc[j][ks] = *(const short8*)(Kp + (size_t)(j * 16 + lr) * 96 + ks * 32 + kg);
  for (int j = 0; j < 8; ++j)
    vc[j] = *(const short8*)(Vt + (size_t)(j * 16 + lr) * 2048 + kg);

  for (int kt = 0; kt < nkt; ++kt) {
    int kv0 = kt * 32;
    // issue next tile's loads now; latency hides under QK+softmax+PV below
    short8 kn[2][3], vn[8];
    if (kt + 1 < nkt) {
      int kv1 = kv0 + 32;
      for (int j = 0; j < 2; ++j)
        for (int ks = 0; ks < 3; ++ks)
          kn[j][ks] = *(const short8*)(Kp + (size_t)(kv1 + j * 16 + lr) * 96 + ks * 32 + kg);
      for (int j = 0; j < 8; ++j)
        vn[j] = *(const short8*)(Vt + (size_t)(j * 16 + lr) * 2048 + kv1 + kg);
    }

    f32x4 s[2][2];
    for (int i = 0; i < 2; ++i)
      for (int j = 0; j < 2; ++j) s[i][j] = f32x4{0.f, 0.f, 0.f, 0.f};
    for (int j = 0; j < 2; ++j)
      for (int ks = 0; ks < 3; ++ks) {
        s[0][j] = mfma16(qfr[0][ks], kc[j][ks], s[0][j]);
        s[1][j] = mfma16(qfr[1][ks], kc[j][ks], s[1][j]);
      }
    bool diag = (kt == nkt - 1);
    for (int i = 0; i < 2; ++i)
      for (int j = 0; j < 2; ++j)
        for (int r = 0; r < 4; ++r) {
          float v = s[i][j][r] * scale;
          if (diag) {
            int qq = q0 + i * 16 + (lane >> 4) * 4 + r;
            int kk = kv0 + j * 16 + lr;
            if (kk > qq) v = -1e30f;
          }
          s[i][j][r] = v;
        }
    for (int i = 0; i < 2; ++i)
      for (int r = 0; r < 4; ++r) {
        float v = fmaxf(s[i][0][r], s[i][1][r]);
        v = fmaxf(v, __shfl_xor(v, 1));
        v = fmaxf(v, __shfl_xor(v, 2));
        v = fmaxf(v, __shfl_xor(v, 4));
        v = fmaxf(v, __shfl_xor(v, 8));
        float mnew = fmaxf(mrow[i][r], v);
        float alpha = __expf(mrow[i][r] - mnew);
        mrow[i][r] = mnew;
        float p0 = __expf(s[i][0][r] - mnew);
        float p1 = __expf(s[i][1][r] - mnew);
        s[i][0][r] = p0; s[i][1][r] = p1;
        float rs = p0 + p1;
        rs += __shfl_xor(rs, 1); rs += __shfl_xor(rs, 2);
        rs += __shfl_xor(rs, 4); rs += __shfl_xor(rs, 8);
        lsum[i][r] = lsum[i][r] * alpha + rs;
        for (int j = 0; j < 8; ++j) o[i][j][r] *= alpha;
      }
    __syncthreads();
    for (int i = 0; i < 2; ++i)
      for (int j = 0; j < 2; ++j)
        for (int r = 0; r < 4; ++r)
          plds[i * 16 + (lane >> 4) * 4 + r][j * 16 + lr] = __float2bfloat16(s[i][j][r]);
    __syncthreads();
    short8 pf0 = *(const short8*)&plds[lr][kg];
    short8 pf1 = *(const short8*)&plds[16 + lr][kg];
    for (int j = 0; j < 8; ++j) {
      o[0][j] = mfma16(pf0, vc[j], o[0][j]);
      o[1][j] = mfma16(pf1, vc[j], o[1][j]);
    }
    // rotate prefetched tile in
    for (int j = 0; j < 2; ++j)
      for (int ks = 0; ks < 3; ++ks) kc[j][ks] = kn[j][ks];
    for (int j = 0; j < 8; ++j) vc[j] = vn[j];
  }
  int b = bh >> 2, h = bh & 3;
  for (int i = 0; i < 2; ++i)
    for (int r = 0; r < 4; ++r) {
      int qq = q0 + i * 16 + (lane >> 4) * 4 + r;
      float inv = 1.f / lsum[i][r];
      size_t base = ((size_t)(b * 2048 + qq)) * 512 + h * 128;
      for (int j = 0; j < 8; ++j)
        attn[base + j * 16 + lr] = __float2bfloat16(o[i][j][r] * inv);
    }
}

// ---------------- rmsnorm #2 ----------------
__global__ __launch_bounds__(256) void k_norm2(const float* __restrict__ x1,
                                               const float* __restrict__ w,
                                               float* __restrict__ x2f,
                                               bf16* __restrict__ x2b) {
  int t = blockIdx.x * 4 + (threadIdx.x >> 6);
  int lane = threadIdx.x & 63;
  const float* row = x1 + (size_t)t * 512;
  float ss = 0.f;
  for (int d = lane; d < 512; d += 64) { float v = row[d]; ss += v * v; }
  for (int o = 32; o > 0; o >>= 1) ss += __shfl_xor(ss, o);
  float rr = rsqrtf(ss / 512.f + 1e-6f);
  for (int d = lane; d < 512; d += 64) {
    float v = row[d] * rr * w[d];
    x2f[(size_t)t * 512 + d] = v;
    x2b[(size_t)t * 512 + d] = __float2bfloat16(v);
  }
}

// ---------------- MoE gating: softmax + top2 -> gates[t][10] ----------------
__global__ __launch_bounds__(256) void k_gating(const float* __restrict__ x2f,
                                                const float* __restrict__ Wg,
                                                float* __restrict__ gates) {
  __shared__ float lg[4][8];
  int wv = threadIdx.x >> 6;
  int t = blockIdx.x * 4 + wv;
  int lane = threadIdx.x & 63;
  int e = lane >> 3, p = lane & 7;
  const float* row = x2f + (size_t)t * 512;
  float sacc = 0.f;
  for (int i = 0; i < 64; ++i) {
    int d = p * 64 + i;
    sacc += row[d] * Wg[d * 8 + e];
  }
  sacc += __shfl_xor(sacc, 1);
  sacc += __shfl_xor(sacc, 2);
  sacc += __shfl_xor(sacc, 4);
  if (p == 0) lg[wv][e] = sacc;
  __syncthreads();
  float pr[8];
  float mx = -1e30f;
  for (int i = 0; i < 8; ++i) { pr[i] = lg[wv][i]; mx = fmaxf(mx, pr[i]); }
  for (int i = 0; i < 8; ++i) pr[i] = __expf(pr[i] - mx);
  int i1 = 0; float v1 = pr[0];
  for (int i = 1; i < 8; ++i) if (pr[i] > v1) { v1 = pr[i]; i1 = i; }
  int i2 = -1; float v2 = -1.f;
  for (int i = 0; i < 8; ++i) if (i != i1 && pr[i] > v2) { v2 = pr[i]; i2 = i; }
  float wsum = v1 + v2;
  if (lane < 10) {
    float g = 1.f;  // shared experts (slots 8,9)
    if (lane < 8) g = (lane == i1) ? v1 / wsum : ((lane == i2) ? v2 / wsum : 0.f);
    gates[(size_t)t * 10 + lane] = g;
  }
}

// ---------------- host ----------------
extern "C" void kernel_launch(void* const* d_in, const int* in_sizes, int n_in,
                              void* d_out, int out_size, void* d_ws, size_t ws_size,
                              hipStream_t stream) {
  const float* x    = (const float*)d_in[0];
  const float* n2w  = (const float*)d_in[1];
  const float* Wdq  = (const float*)d_in[2];
  const float* qnw  = (const float*)d_in[3];
  const float* Wuq  = (const float*)d_in[4];
  const float* Wdkv = (const float*)d_in[5];
  const float* kvnw = (const float*)d_in[6];
  const float* Wukv = (const float*)d_in[7];
  const float* Wo   = (const float*)d_in[8];
  const float* Wg   = (const float*)d_in[9];
  const float* We1  = (const float*)d_in[10];
  const float* We2  = (const float*)d_in[11];
  const float* Ws1  = (const float*)d_in[12];
  const float* Ws2  = (const float*)d_in[13];

  float* out_x  = (float*)d_out;
  float* out_kv = out_x + (size_t)4 * 2048 * 512;

  char* base = (char*)d_ws;
  size_t off = 0;
  auto alloc = [&](size_t bytes) -> void* {
    void* p = base + off;
    off += (bytes + 255) & ~(size_t)255;
    return p;
  };
  const size_t T = 8192;
  bf16*  xb    = (bf16*)alloc(T * 512 * 2);
  bf16*  WcatT = (bf16*)alloc(352 * 512 * 2);
  bf16*  WuqT  = (bf16*)alloc(384 * 192 * 2);
  bf16*  WukvT = (bf16*)alloc(768 * 128 * 2);
  bf16*  WoT   = (bf16*)alloc(512 * 512 * 2);
  bf16*  W1T   = (bf16*)alloc((size_t)10 * 1024 * 512 * 2);
  bf16*  W2T   = (bf16*)alloc((size_t)10 * 512 * 1024 * 2);
  float* tmp0  = (float*)alloc(T * 352 * 4);
  bf16*  cq    = (bf16*)alloc(T * 192 * 2);
  bf16*  kvn   = (bf16*)alloc(T * 128 * 2);
  float* krope = (float*)alloc(T * 32 * 4);
  float* qraw  = (float*)alloc(T * 384 * 4);
  bf16*  kvbig = (bf16*)alloc(T * 768 * 2);
  bf16*  qf    = (bf16*)alloc(T * 384 * 2);
  bf16*  kf    = (bf16*)alloc(T * 384 * 2);
  bf16*  vT    = (bf16*)alloc(T * 512 * 2);
  bf16*  attnb = (bf16*)alloc(T * 512 * 2);
  float* x1f   = (float*)alloc(T * 512 * 4);
  float* x2f   = (float*)alloc(T * 512 * 4);
  bf16*  x2b   = (bf16*)alloc(T * 512 * 2);
  float* gates = (float*)alloc(T * 10 * 4);
  bf16*  Hbuf  = (bf16*)alloc(T * 1024 * 2);
  float* ropet = (float*)alloc(2048 * 32 * 4);
  float* moeacc = x1f;  // alias: x1f is dead after k_norm2

  if (off > ws_size) return;

  // x -> bf16 ; rope table
  k_f32_to_bf16<<<(int)((T * 512 + 255) / 256), 256, 0, stream>>>(x, xb, (int)(T * 512));
  k_rope_table<<<128, 256, 0, stream>>>(ropet);

  // weight transposes (f32 -> bf16, N x K)
  k_transpose<<<dim3(8, 3, 1), 256, 0, stream>>>(Wdq,  WcatT,             512, 192, 512, 0, 0);
  k_transpose<<<dim3(8, 3, 1), 256, 0, stream>>>(Wdkv, WcatT + 192 * 512, 512, 160, 512, 0, 0);
  k_transpose<<<dim3(3, 6, 1), 256, 0, stream>>>(Wuq,  WuqT,  192, 384, 192, 0, 0);
  k_transpose<<<dim3(2, 12, 1), 256, 0, stream>>>(Wukv, WukvT, 128, 768, 128, 0, 0);
  k_transpose<<<dim3(8, 8, 1), 256, 0, stream>>>(Wo,   WoT,   512, 512, 512, 0, 0);
  k_transpose<<<dim3(8, 16, 8), 256, 0, stream>>>(We1, W1T, 512, 1024, 512,
                                                  (size_t)512 * 1024, (size_t)1024 * 512);
  k_transpose<<<dim3(8, 16, 2), 256, 0, stream>>>(Ws1, W1T + (size_t)8 * 1024 * 512, 512, 1024, 512,
                                                  (size_t)512 * 1024, (size_t)1024 * 512);
  k_transpose<<<dim3(16, 8, 8), 256, 0, stream>>>(We2, W2T, 1024, 512, 1024,
                                                  (size_t)1024 * 512, (size_t)512 * 1024);
  k_transpose<<<dim3(16, 8, 2), 256, 0, stream>>>(Ws2, W2T + (size_t)8 * 512 * 1024, 1024, 512, 1024,
                                                  (size_t)1024 * 512, (size_t)512 * 1024);

  // x @ [W_dq | W_dkv] -> tmp0 (f32), then norms/splits (+ f32 kv output)
  k_gemm_nt<<<dim3(64, 3), 256, 0, stream>>>(xb, WcatT, 352, 512, 512, 512, 352, 0, 0,
                                             tmp0, nullptr, nullptr, nullptr, nullptr);
  k_postproj1<<<2048, 256, 0, stream>>>(tmp0, qnw, kvnw, cq, kvn, krope, out_kv);

  // q path
  k_gemm_nt<<<dim3(64, 3), 256, 0, stream>>>(cq, WuqT, 384, 192, 192, 192, 384, 0, 0,
                                             qraw, nullptr, nullptr, nullptr, nullptr);
  k_rope_q<<<12288, 256, 0, stream>>>(qraw, ropet, qf);

  // kv path
  k_gemm_nt<<<dim3(64, 6), 256, 0, stream>>>(kvn, WukvT, 768, 128, 128, 128, 768, 1, 0,
                                             nullptr, kvbig, nullptr, nullptr, nullptr);
  k_make_kf<<<12288, 256, 0, stream>>>(kvbig, krope, ropet, kf);
  k_make_vT<<<dim3(32, 16), 256, 0, stream>>>(kvbig, vT);

  // attention
  k_flash<<<dim3(64, 16), 64, 0, stream>>>(qf, kf, vT, attnb);

  // W_o + residual, norm2, gating
  k_gemm_nt<<<dim3(64, 4), 256, 0, stream>>>(attnb, WoT, 512, 512, 512, 512, 512, 2, 0,
                                             x1f, nullptr, x, nullptr, nullptr);
  k_norm2<<<2048, 256, 0, stream>>>(x1f, n2w, x2f, x2b);
  k_gating<<<2048, 256, 0, stream>>>(x2f, Wg, gates);

  // MoE: dense over 8 routed + 2 shared experts
  for (int e = 0; e < 10; ++e) {
    k_gemm_nt<<<dim3(64, 8), 256, 0, stream>>>(x2b, W1T + (size_t)e * 1024 * 512,
                                               1024, 512, 512, 512, 1024, 3, e,
                                               nullptr, Hbuf, nullptr, nullptr, gates);
    float* dst = (e == 9) ? out_x : moeacc;
    const float* prev = (e == 0) ? x2f : moeacc;
    k_gemm_nt<<<dim3(64, 4), 256, 0, stream>>>(Hbuf, W2T + (size_t)e * 512 * 1024,
                                               512, 1024, 1024, 1024, 512, 4, 0,
                                               dst, nullptr, nullptr, prev, nullptr);
  }
}

// Round 6
// 879.814 us; speedup vs baseline: 3.0928x; 2.9797x over previous
//
#include <hip/hip_runtime.h>
#include <hip/hip_bf16.h>

typedef __hip_bfloat16 bf16;
typedef __attribute__((ext_vector_type(8))) short short8;
typedef __attribute__((ext_vector_type(8))) __bf16 bf16x8;
typedef __attribute__((ext_vector_type(4))) float f32x4;

#define RT_ROWS 17408   // routed capacity (136 tiles)
#define SH0_ROW 17408   // shared expert 0 rows [17408, 25600)
#define SH1_ROW 25600   // shared expert 1 rows [25600, 33792)
#define ROWCAP  33792   // 264 tiles
#define NTILES  264

static __device__ __forceinline__ f32x4 mfma16(short8 a, short8 b, f32x4 c) {
  return __builtin_amdgcn_mfma_f32_16x16x32_bf16(
      __builtin_bit_cast(bf16x8, a), __builtin_bit_cast(bf16x8, b), c, 0, 0, 0);
}

static __device__ __forceinline__ void gload16(const bf16* g, void* l) {
  __builtin_amdgcn_global_load_lds(
      (const __attribute__((address_space(1))) void*)g,
      (__attribute__((address_space(3))) void*)l, 16, 0, 0);
}

static __device__ __forceinline__ float b2f(short s) {
  unsigned u = ((unsigned)(unsigned short)s) << 16;
  return __builtin_bit_cast(float, u);
}

// ---------------- elementwise f32 -> bf16 ----------------
__global__ __launch_bounds__(256) void k_f32_to_bf16(const float* __restrict__ in,
                                                     bf16* __restrict__ out, int n) {
  int i = blockIdx.x * 256 + threadIdx.x;
  if (i < n) out[i] = __float2bfloat16(in[i]);
}

// ---------------- tiled transpose+convert: out[n][k] = in[k][n] ----------------
__global__ __launch_bounds__(256) void k_transpose(const float* __restrict__ in,
                                                   bf16* __restrict__ out,
                                                   int K, int N, int ldo,
                                                   size_t inZ, size_t outZ) {
  in += (size_t)blockIdx.z * inZ;
  out += (size_t)blockIdx.z * outZ;
  __shared__ bf16 t[64][65];
  int k0 = blockIdx.x * 64, n0 = blockIdx.y * 64;
  for (int rep = 0; rep < 16; ++rep) {
    int lin = rep * 256 + threadIdx.x;
    int i = lin >> 6, j = lin & 63;
    if (k0 + i < K && n0 + j < N)
      t[i][j] = __float2bfloat16(in[(size_t)(k0 + i) * N + n0 + j]);
  }
  __syncthreads();
  for (int rep = 0; rep < 16; ++rep) {
    int lin = rep * 256 + threadIdx.x;
    int jj = lin >> 6, ii = lin & 63;
    if (n0 + jj < N && k0 + ii < K)
      out[(size_t)(n0 + jj) * ldo + k0 + ii] = t[ii][jj];
  }
}

// ---------------- dense NT GEMM (gload_lds + chunk-swizzled LDS) ----------------
// Swizzle: LDS physical 16B-chunk pc holds global chunk pc ^ ((row>>1)&3).
// Staging keeps linear LDS dest (gload_lds requirement) and pre-swizzles the
// per-lane GLOBAL source; fragment reads apply the same XOR -> 2-way (free).
// modes: 0 Cf=acc | 1 Cb=acc | 2 Cf=acc+resf
__global__ __launch_bounds__(256) void k_gemm_nt(
    const bf16* __restrict__ A, const bf16* __restrict__ BT,
    int N, int K, int lda, int ldb, int ldc, int mode,
    float* Cf, bf16* Cb, const float* __restrict__ resf) {
  __shared__ __align__(16) bf16 As[128 * 32];
  __shared__ __align__(16) bf16 Bs[128 * 32];
  const int m0 = blockIdx.x * 128, n0 = blockIdx.y * 128;
  const int tid = threadIdx.x, lane = tid & 63, wave = tid >> 6;
  const int wr = (wave >> 1) * 64, wc = (wave & 1) * 64;
  const int lr = lane & 15;
  const int kgs = (((lane >> 4) ^ ((lane >> 1) & 3)) << 3);  // swizzled read chunk
  const int srow = wave * 16 + (lane >> 2);
  const int scol = (((lane & 3) ^ ((lane >> 3) & 3)) << 3);  // swizzled source chunk
  const bf16* Ab = A + (size_t)(m0 + srow) * lda + scol;
  const bf16* Bb = BT + (size_t)(n0 + srow) * ldb + scol;
  char* AsL = (char*)As + wave * 1024;
  char* BsL = (char*)Bs + wave * 1024;

  f32x4 acc[4][4];
  for (int i = 0; i < 4; ++i)
    for (int j = 0; j < 4; ++j) acc[i][j] = f32x4{0.f, 0.f, 0.f, 0.f};

  for (int k0 = 0; k0 < K; k0 += 32) {
    __syncthreads();
    gload16(Ab + k0, AsL);
    gload16(Ab + (size_t)64 * lda + k0, AsL + 4096);
    gload16(Bb + k0, BsL);
    gload16(Bb + (size_t)64 * ldb + k0, BsL + 4096);
    __syncthreads();
    short8 af[4], bfr[4];
    for (int i = 0; i < 4; ++i) af[i] = *(const short8*)&As[(wr + i * 16 + lr) * 32 + kgs];
    for (int j = 0; j < 4; ++j) bfr[j] = *(const short8*)&Bs[(wc + j * 16 + lr) * 32 + kgs];
    for (int i = 0; i < 4; ++i)
      for (int j = 0; j < 4; ++j)
        acc[i][j] = mfma16(af[i], bfr[j], acc[i][j]);
  }

  for (int i = 0; i < 4; ++i) {
    int mb = m0 + wr + i * 16 + (lane >> 4) * 4;
    for (int j = 0; j < 4; ++j) {
      int n = n0 + wc + j * 16 + lr;
      if (n >= N) continue;
      for (int r = 0; r < 4; ++r) {
        size_t idx = (size_t)(mb + r) * ldc + n;
        float v = acc[i][j][r];
        if (mode == 0) Cf[idx] = v;
        else if (mode == 1) Cb[idx] = __float2bfloat16(v);
        else Cf[idx] = v + resf[idx];
      }
    }
  }
}

// ---------------- grouped expert GEMM (same core; expert via tileexp) ----------
// ACT=1: out = bf16(silu(acc)) (up-proj, A rows via rowtok indirection)
// ACT=0: out = bf16(acc)       (down-proj, direct rows)
template <int ACT>
__global__ __launch_bounds__(256) void k_gemm_grouped(
    const bf16* __restrict__ A, const int* __restrict__ rowtok,
    const int* __restrict__ tileexp, const bf16* __restrict__ W, size_t wstride,
    int N, int K, int lda, bf16* __restrict__ out, int ldo) {
  const int ex = tileexp[blockIdx.x];
  if (ex < 0) return;
  __shared__ __align__(16) bf16 As[128 * 32];
  __shared__ __align__(16) bf16 Bs[128 * 32];
  const int m0 = blockIdx.x * 128, n0 = blockIdx.y * 128;
  const int tid = threadIdx.x, lane = tid & 63, wave = tid >> 6;
  const int wr = (wave >> 1) * 64, wc = (wave & 1) * 64;
  const int lr = lane & 15;
  const int kgs = (((lane >> 4) ^ ((lane >> 1) & 3)) << 3);
  const int srow = wave * 16 + (lane >> 2);
  const int scol = (((lane & 3) ^ ((lane >> 3) & 3)) << 3);

  int ar0 = m0 + srow, ar1 = ar0 + 64;
  if (rowtok) {
    int t0 = rowtok[ar0]; ar0 = (t0 < 0) ? 0 : t0;
    int t1 = rowtok[ar1]; ar1 = (t1 < 0) ? 0 : t1;
  }
  const bf16* A0 = A + (size_t)ar0 * lda + scol;
  const bf16* A1 = A + (size_t)ar1 * lda + scol;
  const bf16* BT = W + (size_t)ex * wstride;
  const bf16* B0 = BT + (size_t)(n0 + srow) * K + scol;
  const bf16* B1 = B0 + (size_t)64 * K;
  char* AsL = (char*)As + wave * 1024;
  char* BsL = (char*)Bs + wave * 1024;

  f32x4 acc[4][4];
  for (int i = 0; i < 4; ++i)
    for (int j = 0; j < 4; ++j) acc[i][j] = f32x4{0.f, 0.f, 0.f, 0.f};

  for (int k0 = 0; k0 < K; k0 += 32) {
    __syncthreads();
    gload16(A0 + k0, AsL);
    gload16(A1 + k0, AsL + 4096);
    gload16(B0 + k0, BsL);
    gload16(B1 + k0, BsL + 4096);
    __syncthreads();
    short8 af[4], bfr[4];
    for (int i = 0; i < 4; ++i) af[i] = *(const short8*)&As[(wr + i * 16 + lr) * 32 + kgs];
    for (int j = 0; j < 4; ++j) bfr[j] = *(const short8*)&Bs[(wc + j * 16 + lr) * 32 + kgs];
    for (int i = 0; i < 4; ++i)
      for (int j = 0; j < 4; ++j)
        acc[i][j] = mfma16(af[i], bfr[j], acc[i][j]);
  }

  for (int i = 0; i < 4; ++i) {
    int mb = m0 + wr + i * 16 + (lane >> 4) * 4;
    for (int j = 0; j < 4; ++j) {
      int n = n0 + wc + j * 16 + lr;
      for (int r = 0; r < 4; ++r) {
        float v = acc[i][j][r];
        if (ACT) v = v / (1.f + __expf(-v));
        out[(size_t)(mb + r) * ldo + n] = __float2bfloat16(v);
      }
    }
  }
}

// ---------------- post GEMM0: rmsnorms + split, write kv output (f32) ----------------
__global__ __launch_bounds__(256) void k_postproj1(
    const float* __restrict__ tmp, const float* __restrict__ qnw,
    const float* __restrict__ kvnw, bf16* __restrict__ cq,
    bf16* __restrict__ kvn, float* __restrict__ krope, float* __restrict__ kvout) {
  int t = blockIdx.x * 4 + (threadIdx.x >> 6);
  int lane = threadIdx.x & 63;
  const float* row = tmp + (size_t)t * 352;
  float s1 = 0.f, s2 = 0.f;
  for (int d = lane; d < 192; d += 64) { float v = row[d]; s1 += v * v; }
  for (int d = lane; d < 128; d += 64) { float v = row[192 + d]; s2 += v * v; }
  for (int o = 32; o > 0; o >>= 1) { s1 += __shfl_xor(s1, o); s2 += __shfl_xor(s2, o); }
  float r1 = rsqrtf(s1 / 192.f + 1e-6f);
  float r2 = rsqrtf(s2 / 128.f + 1e-6f);
  for (int d = lane; d < 192; d += 64)
    cq[(size_t)t * 192 + d] = __float2bfloat16(row[d] * r1 * qnw[d]);
  for (int d = lane; d < 128; d += 64)
    kvn[(size_t)t * 128 + d] = __float2bfloat16(row[192 + d] * r2 * kvnw[d]);
  for (int d = lane; d < 160; d += 64)
    kvout[(size_t)t * 160 + d] = row[192 + d];
  if (lane < 32) krope[(size_t)t * 32 + lane] = row[320 + lane];
}

// ---------------- rope cos/sin table ----------------
__global__ __launch_bounds__(256) void k_rope_table(float* __restrict__ tab) {
  int idx = blockIdx.x * 256 + threadIdx.x;  // 2048*16
  int s = idx >> 4, jm = idx & 15;
  float invf = expf(-(float)jm * 0.575646273f);
  float ang = (float)s * invf;
  tab[s * 32 + jm] = cosf(ang);
  tab[s * 32 + 16 + jm] = sinf(ang);
}

// ---------------- q: rope + pack to [bh][s][96] ----------------
__global__ __launch_bounds__(256) void k_rope_q(const float* __restrict__ qraw,
                                                const float* __restrict__ tab,
                                                bf16* __restrict__ qf) {
  int idx = blockIdx.x * 256 + threadIdx.x;
  int t = idx / 384, hd = idx - t * 384;
  int h = hd / 96, d = hd - h * 96;
  int s = t & 2047;
  const float* q = qraw + (size_t)t * 384 + h * 96;
  float v;
  if (d < 64) v = q[d];
  else {
    int j = d - 64, jm = j & 15;
    float c = tab[s * 32 + jm], sn = tab[s * 32 + 16 + jm];
    float x1 = q[64 + jm], x2 = q[80 + jm];
    v = (j < 16) ? (x1 * c - x2 * sn) : (x2 * c + x1 * sn);
  }
  size_t bh = (size_t)(t >> 11) * 4 + h;
  qf[bh * (2048 * 96) + (size_t)s * 96 + d] = __float2bfloat16(v);
}

// ---------------- k: nope copy + shared roped k_rope ----------------
__global__ __launch_bounds__(256) void k_make_kf(const bf16* __restrict__ kvbig,
                                                 const float* __restrict__ krope,
                                                 const float* __restrict__ tab,
                                                 bf16* __restrict__ kf) {
  int idx = blockIdx.x * 256 + threadIdx.x;
  int t = idx / 384, hd = idx - t * 384;
  int h = hd / 96, d = hd - h * 96;
  int s = t & 2047;
  bf16 outv;
  if (d < 64) outv = kvbig[(size_t)t * 768 + h * 192 + d];
  else {
    int j = d - 64, jm = j & 15;
    float c = tab[s * 32 + jm], sn = tab[s * 32 + 16 + jm];
    float x1 = krope[(size_t)t * 32 + jm], x2 = krope[(size_t)t * 32 + 16 + jm];
    float v = (j < 16) ? (x1 * c - x2 * sn) : (x2 * c + x1 * sn);
    outv = __float2bfloat16(v);
  }
  size_t bh = (size_t)(t >> 11) * 4 + h;
  kf[bh * (2048 * 96) + (size_t)s * 96 + d] = outv;
}

// ---------------- v: extract + transpose to [bh][d=128][s=2048] ----------------
__global__ __launch_bounds__(256) void k_make_vT(const bf16* __restrict__ kvbig,
                                                 bf16* __restrict__ vT) {
  __shared__ bf16 t[64][136];
  int bh = blockIdx.y;
  int b = bh >> 2, h = bh & 3;
  int s0 = blockIdx.x * 64;
  for (int rep = 0; rep < 4; ++rep) {
    int lin = rep * 256 + threadIdx.x;
    int i = lin >> 4, jc = (lin & 15) * 8;
    short8 v = *(const short8*)(kvbig + (size_t)(b * 2048 + s0 + i) * 768 + h * 192 + 64 + jc);
    *(short8*)&t[i][jc] = v;
  }
  __syncthreads();
  for (int rep = 0; rep < 32; ++rep) {
    int lin = rep * 256 + threadIdx.x;
    int d = lin >> 6, i = lin & 63;
    vT[((size_t)bh * 128 + d) * 2048 + s0 + i] = t[i][d];
  }
}

// ---------------- flash attention: 1 wave / 16 queries, K/V register prefetch ----
__global__ __launch_bounds__(64, 2) void k_flash(const bf16* __restrict__ qf,
                                                 const bf16* __restrict__ kf,
                                                 const bf16* __restrict__ vT,
                                                 bf16* __restrict__ attn) {
  const int bh = blockIdx.y;
  const int q0 = blockIdx.x * 16;
  const int lane = threadIdx.x;
  const int lr = lane & 15, kg = (lane >> 4) * 8;
  const bf16* Q  = qf + (size_t)bh * (2048 * 96);
  const bf16* Kp = kf + (size_t)bh * (2048 * 96);
  const bf16* Vt = vT + (size_t)bh * (128 * 2048);

  short8 qfr[3];
  for (int ks = 0; ks < 3; ++ks)
    qfr[ks] = *(const short8*)(Q + (size_t)(q0 + lr) * 96 + ks * 32 + kg);

  f32x4 o[8];
  for (int j = 0; j < 8; ++j) o[j] = f32x4{0.f, 0.f, 0.f, 0.f};
  float mrow[4], lsum[4];
  for (int r = 0; r < 4; ++r) { mrow[r] = -1e30f; lsum[r] = 0.f; }

  __shared__ bf16 plds[16][40];
  const float scale = 0.1020620726f;  // 1/sqrt(96)
  const int nkt = q0 / 32 + 1;

  short8 kc[2][3], vc[8];
  for (int j = 0; j < 2; ++j)
    for (int ks = 0; ks < 3; ++ks)
      kc[j][ks] = *(const short8*)(Kp + (size_t)(j * 16 + lr) * 96 + ks * 32 + kg);
  for (int j = 0; j < 8; ++j)
    vc[j] = *(const short8*)(Vt + (size_t)(j * 16 + lr) * 2048 + kg);

  for (int kt = 0; kt < nkt; ++kt) {
    int kv0 = kt * 32;
    short8 kn[2][3], vn[8];
    if (kt + 1 < nkt) {
      int kv1 = kv0 + 32;
      for (int j = 0; j < 2; ++j)
        for (int ks = 0; ks < 3; ++ks)
          kn[j][ks] = *(const short8*)(Kp + (size_t)(kv1 + j * 16 + lr) * 96 + ks * 32 + kg);
      for (int j = 0; j < 8; ++j)
        vn[j] = *(const short8*)(Vt + (size_t)(j * 16 + lr) * 2048 + kv1 + kg);
    }

    f32x4 s[2];
    for (int j = 0; j < 2; ++j) s[j] = f32x4{0.f, 0.f, 0.f, 0.f};
    for (int j = 0; j < 2; ++j)
      for (int ks = 0; ks < 3; ++ks)
        s[j] = mfma16(qfr[ks], kc[j][ks], s[j]);

    bool diag = (kt == nkt - 1);
    for (int j = 0; j < 2; ++j)
      for (int r = 0; r < 4; ++r) {
        float v = s[j][r] * scale;
        if (diag) {
          int qq = q0 + (lane >> 4) * 4 + r;
          int kk = kv0 + j * 16 + lr;
          if (kk > qq) v = -1e30f;
        }
        s[j][r] = v;
      }
    for (int r = 0; r < 4; ++r) {
      float v = fmaxf(s[0][r], s[1][r]);
      v = fmaxf(v, __shfl_xor(v, 1));
      v = fmaxf(v, __shfl_xor(v, 2));
      v = fmaxf(v, __shfl_xor(v, 4));
      v = fmaxf(v, __shfl_xor(v, 8));
      float mnew = fmaxf(mrow[r], v);
      float alpha = __expf(mrow[r] - mnew);
      mrow[r] = mnew;
      float p0 = __expf(s[0][r] - mnew);
      float p1 = __expf(s[1][r] - mnew);
      s[0][r] = p0; s[1][r] = p1;
      float rs = p0 + p1;
      rs += __shfl_xor(rs, 1); rs += __shfl_xor(rs, 2);
      rs += __shfl_xor(rs, 4); rs += __shfl_xor(rs, 8);
      lsum[r] = lsum[r] * alpha + rs;
      for (int j = 0; j < 8; ++j) o[j][r] *= alpha;
    }
    __syncthreads();
    for (int j = 0; j < 2; ++j)
      for (int r = 0; r < 4; ++r)
        plds[(lane >> 4) * 4 + r][j * 16 + lr] = __float2bfloat16(s[j][r]);
    __syncthreads();
    short8 pf = *(const short8*)&plds[lr][kg];
    for (int j = 0; j < 8; ++j)
      o[j] = mfma16(pf, vc[j], o[j]);
    for (int j = 0; j < 2; ++j)
      for (int ks = 0; ks < 3; ++ks) kc[j][ks] = kn[j][ks];
    for (int j = 0; j < 8; ++j) vc[j] = vn[j];
  }
  int b = bh >> 2, h = bh & 3;
  for (int r = 0; r < 4; ++r) {
    int qq = q0 + (lane >> 4) * 4 + r;
    float inv = 1.f / lsum[r];
    size_t baseo = ((size_t)(b * 2048 + qq)) * 512 + h * 128;
    for (int j = 0; j < 8; ++j)
      attn[baseo + j * 16 + lr] = __float2bfloat16(o[j][r] * inv);
  }
}

// ---------------- rmsnorm #2 ----------------
__global__ __launch_bounds__(256) void k_norm2(const float* __restrict__ x1,
                                               const float* __restrict__ w,
                                               float* __restrict__ x2f,
                                               bf16* __restrict__ x2b) {
  int t = blockIdx.x * 4 + (threadIdx.x >> 6);
  int lane = threadIdx.x & 63;
  const float* row = x1 + (size_t)t * 512;
  float ss = 0.f;
  for (int d = lane; d < 512; d += 64) { float v = row[d]; ss += v * v; }
  for (int o = 32; o > 0; o >>= 1) ss += __shfl_xor(ss, o);
  float rr = rsqrtf(ss / 512.f + 1e-6f);
  for (int d = lane; d < 512; d += 64) {
    float v = row[d] * rr * w[d];
    x2f[(size_t)t * 512 + d] = v;
    x2b[(size_t)t * 512 + d] = __float2bfloat16(v);
  }
}

// ---------------- gating: softmax + top2 -> tokexp/tokgate + counts ----------------
__global__ __launch_bounds__(256) void k_gating(const float* __restrict__ x2f,
                                                const float* __restrict__ Wg,
                                                int* __restrict__ tokexp,
                                                float* __restrict__ tokgate,
                                                int* __restrict__ counts) {
  __shared__ float lg[4][8];
  int wv = threadIdx.x >> 6;
  int t = blockIdx.x * 4 + wv;
  int lane = threadIdx.x & 63;
  int e = lane >> 3, p = lane & 7;
  const float* row = x2f + (size_t)t * 512;
  float sacc = 0.f;
  for (int i = 0; i < 64; ++i) {
    int d = p * 64 + i;
    sacc += row[d] * Wg[d * 8 + e];
  }
  sacc += __shfl_xor(sacc, 1);
  sacc += __shfl_xor(sacc, 2);
  sacc += __shfl_xor(sacc, 4);
  if (p == 0) lg[wv][e] = sacc;
  __syncthreads();
  if (lane == 0) {
    float pr[8]; float mx = -1e30f;
    for (int i = 0; i < 8; ++i) { pr[i] = lg[wv][i]; mx = fmaxf(mx, pr[i]); }
    for (int i = 0; i < 8; ++i) pr[i] = __expf(pr[i] - mx);
    int i1 = 0; float v1 = pr[0];
    for (int i = 1; i < 8; ++i) if (pr[i] > v1) { v1 = pr[i]; i1 = i; }
    int i2 = -1; float v2 = -1.f;
    for (int i = 0; i < 8; ++i) if (i != i1 && pr[i] > v2) { v2 = pr[i]; i2 = i; }
    float ws = v1 + v2;
    tokexp[t * 2] = i1; tokexp[t * 2 + 1] = i2;
    tokgate[t * 2] = v1 / ws; tokgate[t * 2 + 1] = v2 / ws;
    atomicAdd(&counts[i1], 1);
    atomicAdd(&counts[i2], 1);
  }
}

// ---------------- MoE setup: segments (128-padded), tileexp, pad rows ------------
__global__ __launch_bounds__(256) void k_moe_setup(const int* __restrict__ counts,
                                                   int* __restrict__ segstart,
                                                   int* __restrict__ tileexp,
                                                   int* __restrict__ rowtok) {
  __shared__ int ss[9], cc[8];
  if (threadIdx.x < 8) cc[threadIdx.x] = counts[threadIdx.x];
  __syncthreads();
  if (threadIdx.x == 0) {
    int off = 0;
    for (int e = 0; e < 8; ++e) { ss[e] = off; off += ((cc[e] + 127) >> 7) << 7; }
    ss[8] = off;
    for (int e = 0; e < 9; ++e) segstart[e] = ss[e];
  }
  __syncthreads();
  for (int tl = threadIdx.x; tl < NTILES; tl += 256) {
    int ex;
    if (tl >= 200) ex = 9;
    else if (tl >= 136) ex = 8;
    else {
      int row = tl * 128; ex = -1;
      for (int i = 0; i < 8; ++i)
        if (row >= ss[i] && row < ss[i + 1]) { ex = i; break; }
    }
    tileexp[tl] = ex;
  }
  for (int e = 0; e < 8; ++e) {
    int cnt = cc[e], cap = ((cnt + 127) >> 7) << 7;
    for (int r = cnt + threadIdx.x; r < cap; r += 256)
      rowtok[ss[e] + r] = -1;
  }
}

// ---------------- assign rows (atomic; output is permutation-invariant) ----------
__global__ __launch_bounds__(256) void k_assign(const int* __restrict__ tokexp,
                                                int* __restrict__ fill,
                                                const int* __restrict__ segstart,
                                                int* __restrict__ rowtok,
                                                int* __restrict__ tokslot) {
  int t = blockIdx.x * 256 + threadIdx.x;  // 8192 tokens
  for (int k = 0; k < 2; ++k) {
    int e = tokexp[t * 2 + k];
    int pos = segstart[e] + atomicAdd(&fill[e], 1);
    rowtok[pos] = t;
    tokslot[t * 2 + k] = pos;
  }
  rowtok[SH0_ROW + t] = t;
  rowtok[SH1_ROW + t] = t;
}

// ---------------- combine: out = x2 + g1*y1 + g2*y2 + yS0 + yS1 ----------------
__global__ __launch_bounds__(256) void k_combine(const float* __restrict__ x2f,
                                                 const bf16* __restrict__ Yg,
                                                 const int* __restrict__ tokslot,
                                                 const float* __restrict__ tokgate,
                                                 float* __restrict__ out_x) {
  int t = blockIdx.x * 4 + (threadIdx.x >> 6);
  int lane = threadIdx.x & 63;
  int s1 = tokslot[t * 2], s2 = tokslot[t * 2 + 1];
  float g1 = tokgate[t * 2], g2 = tokgate[t * 2 + 1];
  int d0 = lane * 8;
  short8 a = *(const short8*)(Yg + (size_t)s1 * 512 + d0);
  short8 b = *(const short8*)(Yg + (size_t)s2 * 512 + d0);
  short8 c = *(const short8*)(Yg + (size_t)(SH0_ROW + t) * 512 + d0);
  short8 d = *(const short8*)(Yg + (size_t)(SH1_ROW + t) * 512 + d0);
  const float* xr = x2f + (size_t)t * 512 + d0;
  float* outr = out_x + (size_t)t * 512 + d0;
  for (int u = 0; u < 8; ++u)
    outr[u] = xr[u] + g1 * b2f(a[u]) + g2 * b2f(b[u]) + b2f(c[u]) + b2f(d[u]);
}

// ---------------- host ----------------
extern "C" void kernel_launch(void* const* d_in, const int* in_sizes, int n_in,
                              void* d_out, int out_size, void* d_ws, size_t ws_size,
                              hipStream_t stream) {
  const float* x    = (const float*)d_in[0];
  const float* n2w  = (const float*)d_in[1];
  const float* Wdq  = (const float*)d_in[2];
  const float* qnw  = (const float*)d_in[3];
  const float* Wuq  = (const float*)d_in[4];
  const float* Wdkv = (const float*)d_in[5];
  const float* kvnw = (const float*)d_in[6];
  const float* Wukv = (const float*)d_in[7];
  const float* Wo   = (const float*)d_in[8];
  const float* Wg   = (const float*)d_in[9];
  const float* We1  = (const float*)d_in[10];
  const float* We2  = (const float*)d_in[11];
  const float* Ws1  = (const float*)d_in[12];
  const float* Ws2  = (const float*)d_in[13];

  float* out_x  = (float*)d_out;
  float* out_kv = out_x + (size_t)4 * 2048 * 512;

  char* base = (char*)d_ws;
  size_t off = 0;
  auto alloc = [&](size_t bytes) -> void* {
    void* p = base + off;
    off += (bytes + 255) & ~(size_t)255;
    return p;
  };
  const size_t T = 8192;
  // ---- persistent region ----
  bf16*  WcatT = (bf16*)alloc(352 * 512 * 2);
  bf16*  WuqT  = (bf16*)alloc(384 * 192 * 2);
  bf16*  WukvT = (bf16*)alloc(768 * 128 * 2);
  bf16*  WoT   = (bf16*)alloc(512 * 512 * 2);
  bf16*  W1T   = (bf16*)alloc((size_t)10 * 1024 * 512 * 2);
  bf16*  W2T   = (bf16*)alloc((size_t)10 * 512 * 1024 * 2);
  float* x2f   = (float*)alloc(T * 512 * 4);
  bf16*  x2b   = (bf16*)alloc(T * 512 * 2);
  int*   tokexp  = (int*)alloc(T * 2 * 4);
  float* tokgate = (float*)alloc(T * 2 * 4);
  int*   tokslot = (int*)alloc(T * 2 * 4);
  int*   rowtok  = (int*)alloc(ROWCAP * 4);
  int*   segstart= (int*)alloc(16 * 4);
  int*   tileexp = (int*)alloc(NTILES * 4);
  int*   cnts    = (int*)alloc(16 * 4);      // counts[8] + fill[8]
  float* ropet   = (float*)alloc(2048 * 32 * 4);

  // ---- scratch region (union of attention-phase and moe-phase) ----
  char* S = base + off;
  size_t soff = 0;
  auto salloc = [&](size_t bytes) -> void* {
    void* p = S + soff;
    soff += (bytes + 255) & ~(size_t)255;
    return p;
  };
  bf16*  xb    = (bf16*)salloc(T * 512 * 2);
  float* tmp0  = (float*)salloc(T * 352 * 4);
  bf16*  cq    = (bf16*)salloc(T * 192 * 2);
  bf16*  kvn   = (bf16*)salloc(T * 128 * 2);
  float* krope = (float*)salloc(T * 32 * 4);
  float* qraw  = (float*)salloc(T * 384 * 4);
  bf16*  kvbig = (bf16*)salloc(T * 768 * 2);
  bf16*  qf    = (bf16*)salloc(T * 384 * 2);
  bf16*  kf    = (bf16*)salloc(T * 384 * 2);
  bf16*  vT    = (bf16*)salloc(T * 512 * 2);
  bf16*  attnb = (bf16*)salloc(T * 512 * 2);
  float* x1f   = (float*)salloc(T * 512 * 4);
  size_t attn_ws = soff;
  // moe phase reuses S from the top (attention buffers are dead by then)
  bf16* Hg = (bf16*)S;                                   // [ROWCAP][1024]
  bf16* Yg = (bf16*)(S + (size_t)ROWCAP * 1024 * 2 + 256); // [ROWCAP][512]
  size_t moe_ws = (size_t)ROWCAP * 1024 * 2 + 256 + (size_t)ROWCAP * 512 * 2;
  size_t need = off + (attn_ws > moe_ws ? attn_ws : moe_ws);
  if (need > ws_size) return;

  hipMemsetAsync(cnts, 0, 64, stream);

  // x -> bf16 ; rope table
  k_f32_to_bf16<<<(int)((T * 512 + 255) / 256), 256, 0, stream>>>(x, xb, (int)(T * 512));
  k_rope_table<<<128, 256, 0, stream>>>(ropet);

  // weight transposes (f32 -> bf16, N x K)
  k_transpose<<<dim3(8, 3, 1), 256, 0, stream>>>(Wdq,  WcatT,             512, 192, 512, 0, 0);
  k_transpose<<<dim3(8, 3, 1), 256, 0, stream>>>(Wdkv, WcatT + 192 * 512, 512, 160, 512, 0, 0);
  k_transpose<<<dim3(3, 6, 1), 256, 0, stream>>>(Wuq,  WuqT,  192, 384, 192, 0, 0);
  k_transpose<<<dim3(2, 12, 1), 256, 0, stream>>>(Wukv, WukvT, 128, 768, 128, 0, 0);
  k_transpose<<<dim3(8, 8, 1), 256, 0, stream>>>(Wo,   WoT,   512, 512, 512, 0, 0);
  k_transpose<<<dim3(8, 16, 8), 256, 0, stream>>>(We1, W1T, 512, 1024, 512,
                                                  (size_t)512 * 1024, (size_t)1024 * 512);
  k_transpose<<<dim3(8, 16, 2), 256, 0, stream>>>(Ws1, W1T + (size_t)8 * 1024 * 512, 512, 1024, 512,
                                                  (size_t)512 * 1024, (size_t)1024 * 512);
  k_transpose<<<dim3(16, 8, 8), 256, 0, stream>>>(We2, W2T, 1024, 512, 1024,
                                                  (size_t)1024 * 512, (size_t)512 * 1024);
  k_transpose<<<dim3(16, 8, 2), 256, 0, stream>>>(Ws2, W2T + (size_t)8 * 512 * 1024, 1024, 512, 1024,
                                                  (size_t)1024 * 512, (size_t)512 * 1024);

  // x @ [W_dq | W_dkv] -> tmp0 (f32), then norms/splits (+ f32 kv output)
  k_gemm_nt<<<dim3(64, 3), 256, 0, stream>>>(xb, WcatT, 352, 512, 512, 512, 352, 0,
                                             tmp0, nullptr, nullptr);
  k_postproj1<<<2048, 256, 0, stream>>>(tmp0, qnw, kvnw, cq, kvn, krope, out_kv);

  // q path
  k_gemm_nt<<<dim3(64, 3), 256, 0, stream>>>(cq, WuqT, 384, 192, 192, 192, 384, 0,
                                             qraw, nullptr, nullptr);
  k_rope_q<<<12288, 256, 0, stream>>>(qraw, ropet, qf);

  // kv path
  k_gemm_nt<<<dim3(64, 6), 256, 0, stream>>>(kvn, WukvT, 768, 128, 128, 128, 768, 1,
                                             nullptr, kvbig, nullptr);
  k_make_kf<<<12288, 256, 0, stream>>>(kvbig, krope, ropet, kf);
  k_make_vT<<<dim3(32, 16), 256, 0, stream>>>(kvbig, vT);

  // attention
  k_flash<<<dim3(128, 16), 64, 0, stream>>>(qf, kf, vT, attnb);

  // W_o + residual, norm2, gating
  k_gemm_nt<<<dim3(64, 4), 256, 0, stream>>>(attnb, WoT, 512, 512, 512, 512, 512, 2,
                                             x1f, nullptr, x);
  k_norm2<<<2048, 256, 0, stream>>>(x1f, n2w, x2f, x2b);
  k_gating<<<2048, 256, 0, stream>>>(x2f, Wg, tokexp, tokgate, cnts);
  k_moe_setup<<<1, 256, 0, stream>>>(cnts, segstart, tileexp, rowtok);
  k_assign<<<32, 256, 0, stream>>>(tokexp, cnts + 8, segstart, rowtok, tokslot);

  // sparse MoE: grouped up (silu) -> grouped down -> combine
  k_gemm_grouped<1><<<dim3(NTILES, 8), 256, 0, stream>>>(
      x2b, rowtok, tileexp, W1T, (size_t)1024 * 512, 1024, 512, 512, Hg, 1024);
  k_gemm_grouped<0><<<dim3(NTILES, 4), 256, 0, stream>>>(
      Hg, nullptr, tileexp, W2T, (size_t)512 * 1024, 512, 1024, 1024, Yg, 512);
  k_combine<<<2048, 256, 0, stream>>>(x2f, Yg, tokslot, tokgate, out_x);
}

// Round 7
// 625.140 us; speedup vs baseline: 4.3527x; 1.4074x over previous
//
#include <hip/hip_runtime.h>
#include <hip/hip_bf16.h>

typedef __hip_bfloat16 bf16;
typedef __attribute__((ext_vector_type(8))) short short8;
typedef __attribute__((ext_vector_type(8))) __bf16 bf16x8;
typedef __attribute__((ext_vector_type(4))) float f32x4;

#define RT_ROWS 17408   // routed capacity (136 tiles)
#define SH0_ROW 17408   // shared expert 0 rows [17408, 25600)
#define SH1_ROW 25600   // shared expert 1 rows [25600, 33792)
#define ROWCAP  33792   // 264 tiles
#define NTILES  264

static __device__ __forceinline__ f32x4 mfma16(short8 a, short8 b, f32x4 c) {
  return __builtin_amdgcn_mfma_f32_16x16x32_bf16(
      __builtin_bit_cast(bf16x8, a), __builtin_bit_cast(bf16x8, b), c, 0, 0, 0);
}

static __device__ __forceinline__ void gload16(const bf16* g, void* l) {
  __builtin_amdgcn_global_load_lds(
      (const __attribute__((address_space(1))) void*)g,
      (__attribute__((address_space(3))) void*)l, 16, 0, 0);
}

static __device__ __forceinline__ float b2f(short s) {
  unsigned u = ((unsigned)(unsigned short)s) << 16;
  return __builtin_bit_cast(float, u);
}

// ---------------- elementwise f32 -> bf16 ----------------
__global__ __launch_bounds__(256) void k_f32_to_bf16(const float* __restrict__ in,
                                                     bf16* __restrict__ out, int n) {
  int i = blockIdx.x * 256 + threadIdx.x;
  if (i < n) out[i] = __float2bfloat16(in[i]);
}

// ---------------- tiled transpose+convert: out[n][k] = in[k][n] ----------------
__global__ __launch_bounds__(256) void k_transpose(const float* __restrict__ in,
                                                   bf16* __restrict__ out,
                                                   int K, int N, int ldo,
                                                   size_t inZ, size_t outZ) {
  in += (size_t)blockIdx.z * inZ;
  out += (size_t)blockIdx.z * outZ;
  __shared__ bf16 t[64][65];
  int k0 = blockIdx.x * 64, n0 = blockIdx.y * 64;
  for (int rep = 0; rep < 16; ++rep) {
    int lin = rep * 256 + threadIdx.x;
    int i = lin >> 6, j = lin & 63;
    if (k0 + i < K && n0 + j < N)
      t[i][j] = __float2bfloat16(in[(size_t)(k0 + i) * N + n0 + j]);
  }
  __syncthreads();
  for (int rep = 0; rep < 16; ++rep) {
    int lin = rep * 256 + threadIdx.x;
    int jj = lin >> 6, ii = lin & 63;
    if (n0 + jj < N && k0 + ii < K)
      out[(size_t)(n0 + jj) * ldo + k0 + ii] = t[ii][jj];
  }
}

// ---------------- dense NT GEMM (gload_lds + chunk-swizzled LDS) ----------------
// modes: 0 Cf=acc | 1 Cb=acc | 2 Cf=acc+resf
__global__ __launch_bounds__(256) void k_gemm_nt(
    const bf16* __restrict__ A, const bf16* __restrict__ BT,
    int N, int K, int lda, int ldb, int ldc, int mode,
    float* Cf, bf16* Cb, const float* __restrict__ resf) {
  __shared__ __align__(16) bf16 As[128 * 32];
  __shared__ __align__(16) bf16 Bs[128 * 32];
  const int m0 = blockIdx.x * 128, n0 = blockIdx.y * 128;
  const int tid = threadIdx.x, lane = tid & 63, wave = tid >> 6;
  const int wr = (wave >> 1) * 64, wc = (wave & 1) * 64;
  const int lr = lane & 15;
  const int kgs = (((lane >> 4) ^ ((lane >> 1) & 3)) << 3);  // swizzled read chunk
  const int srow = wave * 16 + (lane >> 2);
  const int scol = (((lane & 3) ^ ((lane >> 3) & 3)) << 3);  // swizzled source chunk
  const bf16* Ab = A + (size_t)(m0 + srow) * lda + scol;
  const bf16* Bb = BT + (size_t)(n0 + srow) * ldb + scol;
  char* AsL = (char*)As + wave * 1024;
  char* BsL = (char*)Bs + wave * 1024;

  f32x4 acc[4][4];
  for (int i = 0; i < 4; ++i)
    for (int j = 0; j < 4; ++j) acc[i][j] = f32x4{0.f, 0.f, 0.f, 0.f};

  for (int k0 = 0; k0 < K; k0 += 32) {
    __syncthreads();
    gload16(Ab + k0, AsL);
    gload16(Ab + (size_t)64 * lda + k0, AsL + 4096);
    gload16(Bb + k0, BsL);
    gload16(Bb + (size_t)64 * ldb + k0, BsL + 4096);
    __syncthreads();
    short8 af[4], bfr[4];
    for (int i = 0; i < 4; ++i) af[i] = *(const short8*)&As[(wr + i * 16 + lr) * 32 + kgs];
    for (int j = 0; j < 4; ++j) bfr[j] = *(const short8*)&Bs[(wc + j * 16 + lr) * 32 + kgs];
    for (int i = 0; i < 4; ++i)
      for (int j = 0; j < 4; ++j)
        acc[i][j] = mfma16(af[i], bfr[j], acc[i][j]);
  }

  for (int i = 0; i < 4; ++i) {
    int mb = m0 + wr + i * 16 + (lane >> 4) * 4;
    for (int j = 0; j < 4; ++j) {
      int n = n0 + wc + j * 16 + lr;
      if (n >= N) continue;
      for (int r = 0; r < 4; ++r) {
        size_t idx = (size_t)(mb + r) * ldc + n;
        float v = acc[i][j][r];
        if (mode == 0) Cf[idx] = v;
        else if (mode == 1) Cb[idx] = __float2bfloat16(v);
        else Cf[idx] = v + resf[idx];
      }
    }
  }
}

// ---------------- grouped expert GEMM ----------
template <int ACT>
__global__ __launch_bounds__(256) void k_gemm_grouped(
    const bf16* __restrict__ A, const int* __restrict__ rowtok,
    const int* __restrict__ tileexp, const bf16* __restrict__ W, size_t wstride,
    int N, int K, int lda, bf16* __restrict__ out, int ldo) {
  const int ex = tileexp[blockIdx.x];
  if (ex < 0) return;
  __shared__ __align__(16) bf16 As[128 * 32];
  __shared__ __align__(16) bf16 Bs[128 * 32];
  const int m0 = blockIdx.x * 128, n0 = blockIdx.y * 128;
  const int tid = threadIdx.x, lane = tid & 63, wave = tid >> 6;
  const int wr = (wave >> 1) * 64, wc = (wave & 1) * 64;
  const int lr = lane & 15;
  const int kgs = (((lane >> 4) ^ ((lane >> 1) & 3)) << 3);
  const int srow = wave * 16 + (lane >> 2);
  const int scol = (((lane & 3) ^ ((lane >> 3) & 3)) << 3);

  int ar0 = m0 + srow, ar1 = ar0 + 64;
  if (rowtok) {
    int t0 = rowtok[ar0]; ar0 = (t0 < 0) ? 0 : t0;
    int t1 = rowtok[ar1]; ar1 = (t1 < 0) ? 0 : t1;
  }
  const bf16* A0 = A + (size_t)ar0 * lda + scol;
  const bf16* A1 = A + (size_t)ar1 * lda + scol;
  const bf16* BT = W + (size_t)ex * wstride;
  const bf16* B0 = BT + (size_t)(n0 + srow) * K + scol;
  const bf16* B1 = B0 + (size_t)64 * K;
  char* AsL = (char*)As + wave * 1024;
  char* BsL = (char*)Bs + wave * 1024;

  f32x4 acc[4][4];
  for (int i = 0; i < 4; ++i)
    for (int j = 0; j < 4; ++j) acc[i][j] = f32x4{0.f, 0.f, 0.f, 0.f};

  for (int k0 = 0; k0 < K; k0 += 32) {
    __syncthreads();
    gload16(A0 + k0, AsL);
    gload16(A1 + k0, AsL + 4096);
    gload16(B0 + k0, BsL);
    gload16(B1 + k0, BsL + 4096);
    __syncthreads();
    short8 af[4], bfr[4];
    for (int i = 0; i < 4; ++i) af[i] = *(const short8*)&As[(wr + i * 16 + lr) * 32 + kgs];
    for (int j = 0; j < 4; ++j) bfr[j] = *(const short8*)&Bs[(wc + j * 16 + lr) * 32 + kgs];
    for (int i = 0; i < 4; ++i)
      for (int j = 0; j < 4; ++j)
        acc[i][j] = mfma16(af[i], bfr[j], acc[i][j]);
  }

  for (int i = 0; i < 4; ++i) {
    int mb = m0 + wr + i * 16 + (lane >> 4) * 4;
    for (int j = 0; j < 4; ++j) {
      int n = n0 + wc + j * 16 + lr;
      for (int r = 0; r < 4; ++r) {
        float v = acc[i][j][r];
        if (ACT) v = v / (1.f + __expf(-v));
        out[(size_t)(mb + r) * ldo + n] = __float2bfloat16(v);
      }
    }
  }
}

// ---------------- post GEMM0: rmsnorms + split, write kv output (f32) ----------------
__global__ __launch_bounds__(256) void k_postproj1(
    const float* __restrict__ tmp, const float* __restrict__ qnw,
    const float* __restrict__ kvnw, bf16* __restrict__ cq,
    bf16* __restrict__ kvn, float* __restrict__ krope, float* __restrict__ kvout) {
  int t = blockIdx.x * 4 + (threadIdx.x >> 6);
  int lane = threadIdx.x & 63;
  const float* row = tmp + (size_t)t * 352;
  float s1 = 0.f, s2 = 0.f;
  for (int d = lane; d < 192; d += 64) { float v = row[d]; s1 += v * v; }
  for (int d = lane; d < 128; d += 64) { float v = row[192 + d]; s2 += v * v; }
  for (int o = 32; o > 0; o >>= 1) { s1 += __shfl_xor(s1, o); s2 += __shfl_xor(s2, o); }
  float r1 = rsqrtf(s1 / 192.f + 1e-6f);
  float r2 = rsqrtf(s2 / 128.f + 1e-6f);
  for (int d = lane; d < 192; d += 64)
    cq[(size_t)t * 192 + d] = __float2bfloat16(row[d] * r1 * qnw[d]);
  for (int d = lane; d < 128; d += 64)
    kvn[(size_t)t * 128 + d] = __float2bfloat16(row[192 + d] * r2 * kvnw[d]);
  for (int d = lane; d < 160; d += 64)
    kvout[(size_t)t * 160 + d] = row[192 + d];
  if (lane < 32) krope[(size_t)t * 32 + lane] = row[320 + lane];
}

// ---------------- rope cos/sin table ----------------
__global__ __launch_bounds__(256) void k_rope_table(float* __restrict__ tab) {
  int idx = blockIdx.x * 256 + threadIdx.x;  // 2048*16
  int s = idx >> 4, jm = idx & 15;
  float invf = expf(-(float)jm * 0.575646273f);
  float ang = (float)s * invf;
  tab[s * 32 + jm] = cosf(ang);
  tab[s * 32 + 16 + jm] = sinf(ang);
}

// ---------------- q: rope + pack to [bh][s][96] ----------------
__global__ __launch_bounds__(256) void k_rope_q(const float* __restrict__ qraw,
                                                const float* __restrict__ tab,
                                                bf16* __restrict__ qf) {
  int idx = blockIdx.x * 256 + threadIdx.x;
  int t = idx / 384, hd = idx - t * 384;
  int h = hd / 96, d = hd - h * 96;
  int s = t & 2047;
  const float* q = qraw + (size_t)t * 384 + h * 96;
  float v;
  if (d < 64) v = q[d];
  else {
    int j = d - 64, jm = j & 15;
    float c = tab[s * 32 + jm], sn = tab[s * 32 + 16 + jm];
    float x1 = q[64 + jm], x2 = q[80 + jm];
    v = (j < 16) ? (x1 * c - x2 * sn) : (x2 * c + x1 * sn);
  }
  size_t bh = (size_t)(t >> 11) * 4 + h;
  qf[bh * (2048 * 96) + (size_t)s * 96 + d] = __float2bfloat16(v);
}

// ---------------- k: nope copy + shared roped k_rope ----------------
__global__ __launch_bounds__(256) void k_make_kf(const bf16* __restrict__ kvbig,
                                                 const float* __restrict__ krope,
                                                 const float* __restrict__ tab,
                                                 bf16* __restrict__ kf) {
  int idx = blockIdx.x * 256 + threadIdx.x;
  int t = idx / 384, hd = idx - t * 384;
  int h = hd / 96, d = hd - h * 96;
  int s = t & 2047;
  bf16 outv;
  if (d < 64) outv = kvbig[(size_t)t * 768 + h * 192 + d];
  else {
    int j = d - 64, jm = j & 15;
    float c = tab[s * 32 + jm], sn = tab[s * 32 + 16 + jm];
    float x1 = krope[(size_t)t * 32 + jm], x2 = krope[(size_t)t * 32 + 16 + jm];
    float v = (j < 16) ? (x1 * c - x2 * sn) : (x2 * c + x1 * sn);
    outv = __float2bfloat16(v);
  }
  size_t bh = (size_t)(t >> 11) * 4 + h;
  kf[bh * (2048 * 96) + (size_t)s * 96 + d] = outv;
}

// ---------------- v: extract + transpose to [bh][d=128][s=2048] ----------------
__global__ __launch_bounds__(256) void k_make_vT(const bf16* __restrict__ kvbig,
                                                 bf16* __restrict__ vT) {
  __shared__ bf16 t[64][136];
  int bh = blockIdx.y;
  int b = bh >> 2, h = bh & 3;
  int s0 = blockIdx.x * 64;
  for (int rep = 0; rep < 4; ++rep) {
    int lin = rep * 256 + threadIdx.x;
    int i = lin >> 4, jc = (lin & 15) * 8;
    short8 v = *(const short8*)(kvbig + (size_t)(b * 2048 + s0 + i) * 768 + h * 192 + 64 + jc);
    *(short8*)&t[i][jc] = v;
  }
  __syncthreads();
  for (int rep = 0; rep < 32; ++rep) {
    int lin = rep * 256 + threadIdx.x;
    int d = lin >> 6, i = lin & 63;
    vT[((size_t)bh * 128 + d) * 2048 + s0 + i] = t[i][d];
  }
}

// ---------------- flash attention: 1 wave / 16 queries, K/V register prefetch ----
__global__ __launch_bounds__(64, 2) void k_flash(const bf16* __restrict__ qf,
                                                 const bf16* __restrict__ kf,
                                                 const bf16* __restrict__ vT,
                                                 bf16* __restrict__ attn) {
  const int bh = blockIdx.y;
  const int q0 = blockIdx.x * 16;
  const int lane = threadIdx.x;
  const int lr = lane & 15, kg = (lane >> 4) * 8;
  const bf16* Q  = qf + (size_t)bh * (2048 * 96);
  const bf16* Kp = kf + (size_t)bh * (2048 * 96);
  const bf16* Vt = vT + (size_t)bh * (128 * 2048);

  short8 qfr[3];
  for (int ks = 0; ks < 3; ++ks)
    qfr[ks] = *(const short8*)(Q + (size_t)(q0 + lr) * 96 + ks * 32 + kg);

  f32x4 o[8];
  for (int j = 0; j < 8; ++j) o[j] = f32x4{0.f, 0.f, 0.f, 0.f};
  float mrow[4], lsum[4];
  for (int r = 0; r < 4; ++r) { mrow[r] = -1e30f; lsum[r] = 0.f; }

  __shared__ bf16 plds[16][40];
  const float scale = 0.1020620726f;  // 1/sqrt(96)
  const int nkt = q0 / 32 + 1;

  short8 kc[2][3], vc[8];
  for (int j = 0; j < 2; ++j)
    for (int ks = 0; ks < 3; ++ks)
      kc[j][ks] = *(const short8*)(Kp + (size_t)(j * 16 + lr) * 96 + ks * 32 + kg);
  for (int j = 0; j < 8; ++j)
    vc[j] = *(const short8*)(Vt + (size_t)(j * 16 + lr) * 2048 + kg);

  for (int kt = 0; kt < nkt; ++kt) {
    int kv0 = kt * 32;
    short8 kn[2][3], vn[8];
    if (kt + 1 < nkt) {
      int kv1 = kv0 + 32;
      for (int j = 0; j < 2; ++j)
        for (int ks = 0; ks < 3; ++ks)
          kn[j][ks] = *(const short8*)(Kp + (size_t)(kv1 + j * 16 + lr) * 96 + ks * 32 + kg);
      for (int j = 0; j < 8; ++j)
        vn[j] = *(const short8*)(Vt + (size_t)(j * 16 + lr) * 2048 + kv1 + kg);
    }

    f32x4 s[2];
    for (int j = 0; j < 2; ++j) s[j] = f32x4{0.f, 0.f, 0.f, 0.f};
    for (int j = 0; j < 2; ++j)
      for (int ks = 0; ks < 3; ++ks)
        s[j] = mfma16(qfr[ks], kc[j][ks], s[j]);

    bool diag = (kt == nkt - 1);
    for (int j = 0; j < 2; ++j)
      for (int r = 0; r < 4; ++r) {
        float v = s[j][r] * scale;
        if (diag) {
          int qq = q0 + (lane >> 4) * 4 + r;
          int kk = kv0 + j * 16 + lr;
          if (kk > qq) v = -1e30f;
        }
        s[j][r] = v;
      }
    for (int r = 0; r < 4; ++r) {
      float v = fmaxf(s[0][r], s[1][r]);
      v = fmaxf(v, __shfl_xor(v, 1));
      v = fmaxf(v, __shfl_xor(v, 2));
      v = fmaxf(v, __shfl_xor(v, 4));
      v = fmaxf(v, __shfl_xor(v, 8));
      float mnew = fmaxf(mrow[r], v);
      float alpha = __expf(mrow[r] - mnew);
      mrow[r] = mnew;
      float p0 = __expf(s[0][r] - mnew);
      float p1 = __expf(s[1][r] - mnew);
      s[0][r] = p0; s[1][r] = p1;
      float rs = p0 + p1;
      rs += __shfl_xor(rs, 1); rs += __shfl_xor(rs, 2);
      rs += __shfl_xor(rs, 4); rs += __shfl_xor(rs, 8);
      lsum[r] = lsum[r] * alpha + rs;
      for (int j = 0; j < 8; ++j) o[j][r] *= alpha;
    }
    __syncthreads();
    for (int j = 0; j < 2; ++j)
      for (int r = 0; r < 4; ++r)
        plds[(lane >> 4) * 4 + r][j * 16 + lr] = __float2bfloat16(s[j][r]);
    __syncthreads();
    short8 pf = *(const short8*)&plds[lr][kg];
    for (int j = 0; j < 8; ++j)
      o[j] = mfma16(pf, vc[j], o[j]);
    for (int j = 0; j < 2; ++j)
      for (int ks = 0; ks < 3; ++ks) kc[j][ks] = kn[j][ks];
    for (int j = 0; j < 8; ++j) vc[j] = vn[j];
  }
  int b = bh >> 2, h = bh & 3;
  for (int r = 0; r < 4; ++r) {
    int qq = q0 + (lane >> 4) * 4 + r;
    float inv = 1.f / lsum[r];
    size_t baseo = ((size_t)(b * 2048 + qq)) * 512 + h * 128;
    for (int j = 0; j < 8; ++j)
      attn[baseo + j * 16 + lr] = __float2bfloat16(o[j][r] * inv);
  }
}

// ---------------- rmsnorm #2 ----------------
__global__ __launch_bounds__(256) void k_norm2(const float* __restrict__ x1,
                                               const float* __restrict__ w,
                                               float* __restrict__ x2f,
                                               bf16* __restrict__ x2b) {
  int t = blockIdx.x * 4 + (threadIdx.x >> 6);
  int lane = threadIdx.x & 63;
  const float* row = x1 + (size_t)t * 512;
  float ss = 0.f;
  for (int d = lane; d < 512; d += 64) { float v = row[d]; ss += v * v; }
  for (int o = 32; o > 0; o >>= 1) ss += __shfl_xor(ss, o);
  float rr = rsqrtf(ss / 512.f + 1e-6f);
  for (int d = lane; d < 512; d += 64) {
    float v = row[d] * rr * w[d];
    x2f[(size_t)t * 512 + d] = v;
    x2b[(size_t)t * 512 + d] = __float2bfloat16(v);
  }
}

// ---------------- gating: softmax + top2 -> tokexp/tokgate (NO atomics) ----------
// WgT staged in LDS transposed [8][512]: read addr = e*512 + lane + 64*i
// -> bank = lane%32, 2 lanes/bank = conflict-free.
__global__ __launch_bounds__(256) void k_gating(const float* __restrict__ x2f,
                                                const float* __restrict__ Wg,
                                                int* __restrict__ tokexp,
                                                float* __restrict__ tokgate) {
  __shared__ float wgT[8 * 512];
  for (int j = threadIdx.x; j < 4096; j += 256)
    wgT[(j & 7) * 512 + (j >> 3)] = Wg[j];
  __syncthreads();
  int wv = threadIdx.x >> 6, lane = threadIdx.x & 63;
  int t = blockIdx.x * 4 + wv;
  const float* row = x2f + (size_t)t * 512;
  float p[8];
  for (int e = 0; e < 8; ++e) p[e] = 0.f;
  for (int i = 0; i < 8; ++i) {
    int d = lane + 64 * i;
    float rv = row[d];
    for (int e = 0; e < 8; ++e) p[e] += rv * wgT[e * 512 + d];
  }
  for (int o = 32; o > 0; o >>= 1)
    for (int e = 0; e < 8; ++e) p[e] += __shfl_xor(p[e], o);
  if (lane == 0) {
    float mx = -1e30f;
    for (int e = 0; e < 8; ++e) mx = fmaxf(mx, p[e]);
    for (int e = 0; e < 8; ++e) p[e] = __expf(p[e] - mx);
    int i1 = 0; float v1 = p[0];
    for (int e = 1; e < 8; ++e) if (p[e] > v1) { v1 = p[e]; i1 = e; }
    int i2 = -1; float v2 = -1.f;
    for (int e = 0; e < 8; ++e) if (e != i1 && p[e] > v2) { v2 = p[e]; i2 = e; }
    float ws = v1 + v2;
    tokexp[t * 2] = i1; tokexp[t * 2 + 1] = i2;
    tokgate[t * 2] = v1 / ws; tokgate[t * 2 + 1] = v2 / ws;
  }
}

// ---------------- count: LDS histogram, 8 global atomics per block ----------------
__global__ __launch_bounds__(256) void k_count(const int* __restrict__ tokexp,
                                               int* __restrict__ counts) {
  __shared__ int lc[8];
  if (threadIdx.x < 8) lc[threadIdx.x] = 0;
  __syncthreads();
  int i = blockIdx.x * 256 + threadIdx.x;  // 16384 entries, 64 blocks
  atomicAdd(&lc[tokexp[i]], 1);
  __syncthreads();
  if (threadIdx.x < 8) atomicAdd(&counts[threadIdx.x], lc[threadIdx.x]);
}

// ---------------- MoE setup: segments (128-padded), tileexp, pad rows ------------
__global__ __launch_bounds__(256) void k_moe_setup(const int* __restrict__ counts,
                                                   int* __restrict__ segstart,
                                                   int* __restrict__ tileexp,
                                                   int* __restrict__ rowtok) {
  __shared__ int ss[9], cc[8];
  if (threadIdx.x < 8) cc[threadIdx.x] = counts[threadIdx.x];
  __syncthreads();
  if (threadIdx.x == 0) {
    int off = 0;
    for (int e = 0; e < 8; ++e) { ss[e] = off; off += ((cc[e] + 127) >> 7) << 7; }
    ss[8] = off;
    for (int e = 0; e < 9; ++e) segstart[e] = ss[e];
  }
  __syncthreads();
  for (int tl = threadIdx.x; tl < NTILES; tl += 256) {
    int ex;
    if (tl >= 200) ex = 9;
    else if (tl >= 136) ex = 8;
    else {
      int row = tl * 128; ex = -1;
      for (int i = 0; i < 8; ++i)
        if (row >= ss[i] && row < ss[i + 1]) { ex = i; break; }
    }
    tileexp[tl] = ex;
  }
  for (int e = 0; e < 8; ++e) {
    int cnt = cc[e], cap = ((cnt + 127) >> 7) << 7;
    for (int r = cnt + threadIdx.x; r < cap; r += 256)
      rowtok[ss[e] + r] = -1;
  }
}

// ---------------- assign rows: per-block LDS rank + 8 global atomics/block -------
// (row order within an expert segment is nondeterministic, but outputs are
// permutation-invariant: each token's row value is position-independent and
// gathered back via tokslot.)
__global__ __launch_bounds__(256) void k_assign(const int* __restrict__ tokexp,
                                                int* __restrict__ fill,
                                                const int* __restrict__ segstart,
                                                int* __restrict__ rowtok,
                                                int* __restrict__ tokslot) {
  __shared__ int lcnt[8], lbase[8];
  if (threadIdx.x < 8) lcnt[threadIdx.x] = 0;
  __syncthreads();
  int t = blockIdx.x * 256 + threadIdx.x;  // 8192 tokens, 32 blocks
  int e0 = tokexp[t * 2], e1 = tokexp[t * 2 + 1];
  int r0 = atomicAdd(&lcnt[e0], 1);
  int r1 = atomicAdd(&lcnt[e1], 1);
  __syncthreads();
  if (threadIdx.x < 8) lbase[threadIdx.x] = atomicAdd(&fill[threadIdx.x], lcnt[threadIdx.x]);
  __syncthreads();
  int p0 = segstart[e0] + lbase[e0] + r0;
  int p1 = segstart[e1] + lbase[e1] + r1;
  rowtok[p0] = t; rowtok[p1] = t;
  tokslot[t * 2] = p0; tokslot[t * 2 + 1] = p1;
  rowtok[SH0_ROW + t] = t;
  rowtok[SH1_ROW + t] = t;
}

// ---------------- combine: out = x2 + g1*y1 + g2*y2 + yS0 + yS1 ----------------
__global__ __launch_bounds__(256) void k_combine(const float* __restrict__ x2f,
                                                 const bf16* __restrict__ Yg,
                                                 const int* __restrict__ tokslot,
                                                 const float* __restrict__ tokgate,
                                                 float* __restrict__ out_x) {
  int t = blockIdx.x * 4 + (threadIdx.x >> 6);
  int lane = threadIdx.x & 63;
  int s1 = tokslot[t * 2], s2 = tokslot[t * 2 + 1];
  float g1 = tokgate[t * 2], g2 = tokgate[t * 2 + 1];
  int d0 = lane * 8;
  short8 a = *(const short8*)(Yg + (size_t)s1 * 512 + d0);
  short8 b = *(const short8*)(Yg + (size_t)s2 * 512 + d0);
  short8 c = *(const short8*)(Yg + (size_t)(SH0_ROW + t) * 512 + d0);
  short8 d = *(const short8*)(Yg + (size_t)(SH1_ROW + t) * 512 + d0);
  const float* xr = x2f + (size_t)t * 512 + d0;
  float* outr = out_x + (size_t)t * 512 + d0;
  for (int u = 0; u < 8; ++u)
    outr[u] = xr[u] + g1 * b2f(a[u]) + g2 * b2f(b[u]) + b2f(c[u]) + b2f(d[u]);
}

// ---------------- host ----------------
extern "C" void kernel_launch(void* const* d_in, const int* in_sizes, int n_in,
                              void* d_out, int out_size, void* d_ws, size_t ws_size,
                              hipStream_t stream) {
  const float* x    = (const float*)d_in[0];
  const float* n2w  = (const float*)d_in[1];
  const float* Wdq  = (const float*)d_in[2];
  const float* qnw  = (const float*)d_in[3];
  const float* Wuq  = (const float*)d_in[4];
  const float* Wdkv = (const float*)d_in[5];
  const float* kvnw = (const float*)d_in[6];
  const float* Wukv = (const float*)d_in[7];
  const float* Wo   = (const float*)d_in[8];
  const float* Wg   = (const float*)d_in[9];
  const float* We1  = (const float*)d_in[10];
  const float* We2  = (const float*)d_in[11];
  const float* Ws1  = (const float*)d_in[12];
  const float* Ws2  = (const float*)d_in[13];

  float* out_x  = (float*)d_out;
  float* out_kv = out_x + (size_t)4 * 2048 * 512;

  char* base = (char*)d_ws;
  size_t off = 0;
  auto alloc = [&](size_t bytes) -> void* {
    void* p = base + off;
    off += (bytes + 255) & ~(size_t)255;
    return p;
  };
  const size_t T = 8192;
  // ---- persistent region ----
  bf16*  WcatT = (bf16*)alloc(352 * 512 * 2);
  bf16*  WuqT  = (bf16*)alloc(384 * 192 * 2);
  bf16*  WukvT = (bf16*)alloc(768 * 128 * 2);
  bf16*  WoT   = (bf16*)alloc(512 * 512 * 2);
  bf16*  W1T   = (bf16*)alloc((size_t)10 * 1024 * 512 * 2);
  bf16*  W2T   = (bf16*)alloc((size_t)10 * 512 * 1024 * 2);
  float* x2f   = (float*)alloc(T * 512 * 4);
  bf16*  x2b   = (bf16*)alloc(T * 512 * 2);
  int*   tokexp  = (int*)alloc(T * 2 * 4);
  float* tokgate = (float*)alloc(T * 2 * 4);
  int*   tokslot = (int*)alloc(T * 2 * 4);
  int*   rowtok  = (int*)alloc(ROWCAP * 4);
  int*   segstart= (int*)alloc(16 * 4);
  int*   tileexp = (int*)alloc(NTILES * 4);
  int*   cnts    = (int*)alloc(16 * 4);      // counts[8] + fill[8]
  float* ropet   = (float*)alloc(2048 * 32 * 4);

  // ---- scratch region (union of attention-phase and moe-phase) ----
  char* S = base + off;
  size_t soff = 0;
  auto salloc = [&](size_t bytes) -> void* {
    void* p = S + soff;
    soff += (bytes + 255) & ~(size_t)255;
    return p;
  };
  bf16*  xb    = (bf16*)salloc(T * 512 * 2);
  float* tmp0  = (float*)salloc(T * 352 * 4);
  bf16*  cq    = (bf16*)salloc(T * 192 * 2);
  bf16*  kvn   = (bf16*)salloc(T * 128 * 2);
  float* krope = (float*)salloc(T * 32 * 4);
  float* qraw  = (float*)salloc(T * 384 * 4);
  bf16*  kvbig = (bf16*)salloc(T * 768 * 2);
  bf16*  qf    = (bf16*)salloc(T * 384 * 2);
  bf16*  kf    = (bf16*)salloc(T * 384 * 2);
  bf16*  vT    = (bf16*)salloc(T * 512 * 2);
  bf16*  attnb = (bf16*)salloc(T * 512 * 2);
  float* x1f   = (float*)salloc(T * 512 * 4);
  size_t attn_ws = soff;
  // moe phase reuses S from the top (attention buffers are dead by then)
  bf16* Hg = (bf16*)S;                                     // [ROWCAP][1024]
  bf16* Yg = (bf16*)(S + (size_t)ROWCAP * 1024 * 2 + 256); // [ROWCAP][512]
  size_t moe_ws = (size_t)ROWCAP * 1024 * 2 + 256 + (size_t)ROWCAP * 512 * 2;
  size_t need = off + (attn_ws > moe_ws ? attn_ws : moe_ws);
  if (need > ws_size) return;

  hipMemsetAsync(cnts, 0, 64, stream);

  // x -> bf16 ; rope table
  k_f32_to_bf16<<<(int)((T * 512 + 255) / 256), 256, 0, stream>>>(x, xb, (int)(T * 512));
  k_rope_table<<<128, 256, 0, stream>>>(ropet);

  // weight transposes (f32 -> bf16, N x K)
  k_transpose<<<dim3(8, 3, 1), 256, 0, stream>>>(Wdq,  WcatT,             512, 192, 512, 0, 0);
  k_transpose<<<dim3(8, 3, 1), 256, 0, stream>>>(Wdkv, WcatT + 192 * 512, 512, 160, 512, 0, 0);
  k_transpose<<<dim3(3, 6, 1), 256, 0, stream>>>(Wuq,  WuqT,  192, 384, 192, 0, 0);
  k_transpose<<<dim3(2, 12, 1), 256, 0, stream>>>(Wukv, WukvT, 128, 768, 128, 0, 0);
  k_transpose<<<dim3(8, 8, 1), 256, 0, stream>>>(Wo,   WoT,   512, 512, 512, 0, 0);
  k_transpose<<<dim3(8, 16, 8), 256, 0, stream>>>(We1, W1T, 512, 1024, 512,
                                                  (size_t)512 * 1024, (size_t)1024 * 512);
  k_transpose<<<dim3(8, 16, 2), 256, 0, stream>>>(Ws1, W1T + (size_t)8 * 1024 * 512, 512, 1024, 512,
                                                  (size_t)512 * 1024, (size_t)1024 * 512);
  k_transpose<<<dim3(16, 8, 8), 256, 0, stream>>>(We2, W2T, 1024, 512, 1024,
                                                  (size_t)1024 * 512, (size_t)512 * 1024);
  k_transpose<<<dim3(16, 8, 2), 256, 0, stream>>>(Ws2, W2T + (size_t)8 * 512 * 1024, 1024, 512, 1024,
                                                  (size_t)1024 * 512, (size_t)512 * 1024);

  // x @ [W_dq | W_dkv] -> tmp0 (f32), then norms/splits (+ f32 kv output)
  k_gemm_nt<<<dim3(64, 3), 256, 0, stream>>>(xb, WcatT, 352, 512, 512, 512, 352, 0,
                                             tmp0, nullptr, nullptr);
  k_postproj1<<<2048, 256, 0, stream>>>(tmp0, qnw, kvnw, cq, kvn, krope, out_kv);

  // q path
  k_gemm_nt<<<dim3(64, 3), 256, 0, stream>>>(cq, WuqT, 384, 192, 192, 192, 384, 0,
                                             qraw, nullptr, nullptr);
  k_rope_q<<<12288, 256, 0, stream>>>(qraw, ropet, qf);

  // kv path
  k_gemm_nt<<<dim3(64, 6), 256, 0, stream>>>(kvn, WukvT, 768, 128, 128, 128, 768, 1,
                                             nullptr, kvbig, nullptr);
  k_make_kf<<<12288, 256, 0, stream>>>(kvbig, krope, ropet, kf);
  k_make_vT<<<dim3(32, 16), 256, 0, stream>>>(kvbig, vT);

  // attention
  k_flash<<<dim3(128, 16), 64, 0, stream>>>(qf, kf, vT, attnb);

  // W_o + residual, norm2, gating (no atomics), count, setup, assign
  k_gemm_nt<<<dim3(64, 4), 256, 0, stream>>>(attnb, WoT, 512, 512, 512, 512, 512, 2,
                                             x1f, nullptr, x);
  k_norm2<<<2048, 256, 0, stream>>>(x1f, n2w, x2f, x2b);
  k_gating<<<2048, 256, 0, stream>>>(x2f, Wg, tokexp, tokgate);
  k_count<<<64, 256, 0, stream>>>(tokexp, cnts);
  k_moe_setup<<<1, 256, 0, stream>>>(cnts, segstart, tileexp, rowtok);
  k_assign<<<32, 256, 0, stream>>>(tokexp, cnts + 8, segstart, rowtok, tokslot);

  // sparse MoE: grouped up (silu) -> grouped down -> combine
  k_gemm_grouped<1><<<dim3(NTILES, 8), 256, 0, stream>>>(
      x2b, rowtok, tileexp, W1T, (size_t)1024 * 512, 1024, 512, 512, Hg, 1024);
  k_gemm_grouped<0><<<dim3(NTILES, 4), 256, 0, stream>>>(
      Hg, nullptr, tileexp, W2T, (size_t)512 * 1024, 512, 1024, 1024, Yg, 512);
  k_combine<<<2048, 256, 0, stream>>>(x2f, Yg, tokslot, tokgate, out_x);
}